// Round 1
// 541.567 us; speedup vs baseline: 1.0041x; 1.0041x over previous
//
#include <hip/hip_runtime.h>
#include <hip/hip_bf16.h>

typedef __attribute__((ext_vector_type(8))) short short8;
typedef __attribute__((ext_vector_type(4))) float f32x4;

#define NTOK 8192
#define HCH  2048
#define DDIM 128
#define NSPLIT 8
#define KPS   (NTOK / NSPLIT)     // 1024
#define NITER (KPS / 64)          // 16

__device__ __forceinline__ unsigned short f2bf(float f) {
    __hip_bfloat16 h = __float2bfloat16(f);
    return *reinterpret_cast<unsigned short*>(&h);
}
__device__ __forceinline__ unsigned short f2h(float f) {
    _Float16 h = (_Float16)f;
    return *reinterpret_cast<unsigned short*>(&h);
}

// Direct global->LDS (width 16). LDS dest must be linear in lane order
// (wave-uniform base + lane*16); swizzle is applied on the SOURCE address.
__device__ __forceinline__ void gload_lds16(const void* g, void* l) {
    __builtin_amdgcn_global_load_lds(
        reinterpret_cast<const __attribute__((address_space(1))) unsigned int*>(
            reinterpret_cast<uintptr_t>(g)),
        reinterpret_cast<__attribute__((address_space(3))) unsigned int*>(
            reinterpret_cast<uintptr_t>(l)),
        16, 0, 0);
}

// ---------------------------------------------------------------------------
// Kernel 0: runtime dtype detection (one wave, parallel).
// ---------------------------------------------------------------------------
__global__ void detect_kernel(const unsigned int* __restrict__ X,
                              const unsigned int* __restrict__ M,
                              int* __restrict__ flags)
{
    const int lane = threadIdx.x & 63;
    unsigned int e = (X[lane] >> 7) & 0xFF;
    unsigned long long hb = __ballot(e >= 110 && e <= 140);

    bool w_ok = true, h_ok = true, b_ok = true;
#pragma unroll
    for (int i = 0; i < 16; i++) {
        unsigned int u = M[lane + 64 * i];
        if (!(u == 0u || u == 1u || u == 0x3F800000u)) w_ok = false;
        unsigned int h0 = u & 0xFFFFu, h1 = u >> 16;
        bool o0 = (h0 == 0u || h0 == 0x3F80u || h0 == 0x3C00u || h0 == 1u);
        bool o1 = (h1 == 0u || h1 == 0x3F80u || h1 == 0x3C00u || h1 == 1u);
        if (!(o0 && o1)) h_ok = false;
        unsigned int b0 = u & 0xFF, b1 = (u >> 8) & 0xFF,
                     b2 = (u >> 16) & 0xFF, b3 = u >> 24;
        if (b0 > 1u || b1 > 1u || b2 > 1u || b3 > 1u) b_ok = false;
    }
    bool allw = __all(w_ok), allh = __all(h_ok), allb = __all(b_ok);
    if (lane == 0) {
        flags[0] = (__popcll(hb) < 32) ? 1 : 0;
        flags[1] = allw ? 0 : (allb ? 1 : (allh ? 2 : 3));
    }
}

// ---------------------------------------------------------------------------
// Kernel 0b: W -> bf16.
// ---------------------------------------------------------------------------
__global__ __launch_bounds__(256) void conv_w(
    const void* __restrict__ Wv, const int* __restrict__ flags,
    unsigned short* __restrict__ Wbf)
{
    int t = blockIdx.x * 256 + threadIdx.x;
    size_t off = (size_t)t * 8;
    if (flags[0] != 0) {
        const float* Wf = (const float*)Wv;
        float4 a = *reinterpret_cast<const float4*>(Wf + off);
        float4 b = *reinterpret_cast<const float4*>(Wf + off + 4);
        unsigned short o[8] = { f2bf(a.x), f2bf(a.y), f2bf(a.z), f2bf(a.w),
                                f2bf(b.x), f2bf(b.y), f2bf(b.z), f2bf(b.w) };
        *reinterpret_cast<uint4*>(Wbf + off) = *reinterpret_cast<uint4*>(o);
    } else {
        *reinterpret_cast<uint4*>(Wbf + off) =
            *reinterpret_cast<const uint4*>((const unsigned short*)Wv + off);
    }
}

// ---------------------------------------------------------------------------
// Kernel 0c: mask -> 1 bit/elem (thread per output byte, coalesced).
// ---------------------------------------------------------------------------
__global__ __launch_bounds__(256) void mask_pack(
    const void* __restrict__ maskv, const int* __restrict__ flags,
    unsigned char* __restrict__ Mp)
{
    const int mmode = flags[1];
    const int NB = NTOK * (NTOK / 8);
    int t0 = blockIdx.x * 256 + threadIdx.x;
    for (int b = t0; b < NB; b += 2048 * 256) {
        unsigned int byte = 0;
        if (mmode == 0) {
            const uint4* p = reinterpret_cast<const uint4*>(
                (const unsigned int*)maskv + (size_t)b * 8);
            uint4 a = p[0], c = p[1];
            byte = (a.x != 0u) | ((a.y != 0u) << 1) | ((a.z != 0u) << 2) | ((a.w != 0u) << 3)
                 | ((c.x != 0u) << 4) | ((c.y != 0u) << 5) | ((c.z != 0u) << 6) | ((c.w != 0u) << 7);
        } else if (mmode == 1) {
            unsigned long long v = *reinterpret_cast<const unsigned long long*>(
                (const unsigned char*)maskv + (size_t)b * 8);
#pragma unroll
            for (int k = 0; k < 8; k++)
                byte |= (((v >> (8 * k)) & 0xFFull) != 0ull) << k;
        } else if (mmode == 2) {
            uint4 a = *reinterpret_cast<const uint4*>(
                (const unsigned short*)maskv + (size_t)b * 8);
            byte = ((a.x & 0xFFFFu) != 0u) | ((a.x >> 16 != 0u) << 1)
                 | (((a.y & 0xFFFFu) != 0u) << 2) | ((a.y >> 16 != 0u) << 3)
                 | (((a.z & 0xFFFFu) != 0u) << 4) | ((a.z >> 16 != 0u) << 5)
                 | (((a.w & 0xFFFFu) != 0u) << 6) | ((a.w >> 16 != 0u) << 7);
        } else {
            byte = ((const unsigned char*)maskv)[b];
        }
        Mp[b] = (unsigned char)byte;
    }
}

// ---------------------------------------------------------------------------
// Kernel 1: QKV projection (unchanged).
// ---------------------------------------------------------------------------
__global__ __launch_bounds__(256) void qkv_gemm(
    const void* __restrict__ Xv, const unsigned short* __restrict__ Wbf,
    const int* __restrict__ flags,
    unsigned short* __restrict__ Qb, unsigned short* __restrict__ Kb,
    unsigned short* __restrict__ Vb)
{
    __shared__ unsigned short Wsm[128 * 64];
    __shared__ unsigned short Xsm[32 * 64];
    const int tid  = threadIdx.x;
    const int lane = tid & 63, w = tid >> 6;
    const int c = lane & 15, g = lane >> 4;
    const int q0 = blockIdx.x * 32;
    const int n0 = blockIdx.y * 128;
    const bool f32in = (flags[0] != 0);
    const float*          Xf = (const float*)Xv;
    const unsigned short* Xb = (const unsigned short*)Xv;

    f32x4 acc[4];
#pragma unroll
    for (int i = 0; i < 4; i++) acc[i] = (f32x4){0.f, 0.f, 0.f, 0.f};

    const int xrow = tid >> 3, xc8 = tid & 7;
    const int arow = (w & 1) * 16 + c;

    for (int kk = 0; kk < HCH; kk += 64) {
        __syncthreads();
#pragma unroll
        for (int i = 0; i < 4; i++) {
            int cid = tid + 256 * i;
            int n = cid >> 3, c8 = cid & 7;
            uint4 v = *reinterpret_cast<const uint4*>(Wbf + (size_t)(n0 + n) * HCH + kk + c8 * 8);
            *reinterpret_cast<uint4*>(&Wsm[(n * 8 + (c8 ^ (n & 7))) * 8]) = v;
        }
        {
            unsigned short o[8];
            if (f32in) {
                const float* p = Xf + (size_t)(q0 + xrow) * HCH + kk + xc8 * 8;
                float4 a = *reinterpret_cast<const float4*>(p);
                float4 b = *reinterpret_cast<const float4*>(p + 4);
                o[0]=f2bf(a.x); o[1]=f2bf(a.y); o[2]=f2bf(a.z); o[3]=f2bf(a.w);
                o[4]=f2bf(b.x); o[5]=f2bf(b.y); o[6]=f2bf(b.z); o[7]=f2bf(b.w);
            } else {
                *reinterpret_cast<uint4*>(o) =
                    *reinterpret_cast<const uint4*>(Xb + (size_t)(q0 + xrow) * HCH + kk + xc8 * 8);
            }
            *reinterpret_cast<uint4*>(&Xsm[(xrow * 8 + (xc8 ^ (xrow & 7))) * 8]) =
                *reinterpret_cast<uint4*>(o);
        }
        __syncthreads();
#pragma unroll
        for (int ks = 0; ks < 2; ks++) {
            short8 af = *reinterpret_cast<const short8*>(
                &Xsm[(arow * 8 + ((ks * 4 + g) ^ (c & 7))) * 8]);
#pragma unroll
            for (int nt = 0; nt < 4; nt++) {
                int n = (w >> 1) * 64 + nt * 16 + c;
                short8 bf = *reinterpret_cast<const short8*>(
                    &Wsm[(n * 8 + ((ks * 4 + g) ^ (c & 7))) * 8]);
                acc[nt] = __builtin_amdgcn_mfma_f32_16x16x32_bf16(af, bf, acc[nt], 0, 0, 0);
            }
        }
    }
    unsigned short* dst = (blockIdx.y == 0) ? Qb : (blockIdx.y == 1) ? Kb : Vb;
#pragma unroll
    for (int nt = 0; nt < 4; nt++) {
        int n = (w >> 1) * 64 + nt * 16 + c;
#pragma unroll
        for (int r = 0; r < 4; r++) {
            int rr = q0 + (w & 1) * 16 + g * 4 + r;
            dst[(size_t)rr * DDIM + n] = f2bf(acc[nt][r]);
        }
    }
}

// ---------------------------------------------------------------------------
// Kernel 2: V -> VT (unchanged).
// ---------------------------------------------------------------------------
__global__ __launch_bounds__(256) void vtrans(
    const unsigned short* __restrict__ V, unsigned short* __restrict__ VT)
{
    __shared__ unsigned short T[32 * 33];
    const int t = threadIdx.x;
    const int k0 = blockIdx.x * 32, d0 = blockIdx.y * 32;
    {
        int key = t >> 3, dq = (t & 7) * 4;
        ushort4 v = *reinterpret_cast<const ushort4*>(V + (size_t)(k0 + key) * DDIM + d0 + dq);
        T[(dq + 0) * 33 + key] = v.x;
        T[(dq + 1) * 33 + key] = v.y;
        T[(dq + 2) * 33 + key] = v.z;
        T[(dq + 3) * 33 + key] = v.w;
    }
    __syncthreads();
    {
        int d = t >> 3, kq = (t & 7) * 4;
        ushort4 o;
        o.x = T[d * 33 + kq + 0]; o.y = T[d * 33 + kq + 1];
        o.z = T[d * 33 + kq + 2]; o.w = T[d * 33 + kq + 3];
        *reinterpret_cast<ushort4*>(VT + (size_t)(d0 + d) * NTOK + k0 + kq) = o;
    }
}

// ---------------------------------------------------------------------------
// Kernel 3: flash partials v6. 2-phase double-buffered staging via
// global_load_lds (width 16): linear LDS dest + inverse-swizzled per-lane
// global SOURCE (same XOR involution the read side uses), issued BEFORE the
// compute of the current tile; one __syncthreads per iter drains it. Removes
// the global->reg->ds_write round-trip and one barrier per iteration.
// ---------------------------------------------------------------------------
__global__ __launch_bounds__(256) void attn_part(
    const unsigned short* __restrict__ Qb, const unsigned short* __restrict__ Kb,
    const unsigned short* __restrict__ VT, const unsigned long long* __restrict__ Mp,
    _Float16* __restrict__ Opart, float* __restrict__ lpart)
{
    __shared__ unsigned short Ksm[2][64 * 128];   // 2 x 16 KB
    __shared__ unsigned short Vsm[2][128 * 64];   // 2 x 16 KB
    __shared__ unsigned short Psm[4 * 16 * 64];   // 8 KB  (72 KB total -> 2 blk/CU)
    const int tid  = threadIdx.x;
    const int lane = tid & 63, w = tid >> 6;
    const int c = lane & 15, g = lane >> 4;
    const int split = blockIdx.x;              // 0..7
    const int qb    = blockIdx.y;              // 0..63
    const int q0 = qb * 128;
    const int kbase = split * KPS;
    const int tb0 = kbase >> 6;
    unsigned short* Pw = &Psm[w * 16 * 64];

    // Stage K tile [64][128] + VT tile [128][64] for tile tt into buffer b.
    // LDS slot (row, cc) must hold global chunk (cc ^ (row & m)) — identical
    // effective layout to the old ds_write swizzle, so reads are unchanged.
    auto stage = [&](int b, int tt) {
        const int k0s = kbase + tt * 64;
#pragma unroll
        for (int i = 0; i < 4; i++) {
            int cid = tid + 256 * i;
            int rowk = cid >> 4, c16 = cid & 15;
            gload_lds16(Kb + (size_t)(k0s + rowk) * DDIM + ((c16 ^ (rowk & 15)) * 8),
                        &Ksm[b][cid * 8]);
        }
#pragma unroll
        for (int i = 0; i < 4; i++) {
            int cid = tid + 256 * i;
            int d = cid >> 3, c8 = cid & 7;
            gload_lds16(VT + (size_t)d * NTOK + k0s + ((c8 ^ (d & 7)) * 8),
                        &Vsm[b][cid * 8]);
        }
    };

    // Q fragments for both row-tiles (loop-invariant)
    short8 qf[2][4];
#pragma unroll
    for (int rt = 0; rt < 2; rt++)
#pragma unroll
        for (int ks = 0; ks < 4; ks++)
            qf[rt][ks] = *reinterpret_cast<const short8*>(
                Qb + (size_t)(q0 + w * 32 + rt * 16 + c) * DDIM + ks * 32 + g * 8);

    short8 ones;
#pragma unroll
    for (int i = 0; i < 8; i++) ones[i] = (short)0x3F80;   // bf16 1.0

    f32x4 accO[2][8];
#pragma unroll
    for (int rt = 0; rt < 2; rt++)
#pragma unroll
        for (int i = 0; i < 8; i++) accO[rt][i] = (f32x4){0.f, 0.f, 0.f, 0.f};
    f32x4 accL[2] = {(f32x4){0.f,0.f,0.f,0.f}, (f32x4){0.f,0.f,0.f,0.f}};

    unsigned long long mp[2][4], mpn[2][4];
#pragma unroll
    for (int rt = 0; rt < 2; rt++)
#pragma unroll
        for (int r = 0; r < 4; r++)
            mp[rt][r] = Mp[(size_t)(q0 + w * 32 + rt * 16 + g * 4 + r) * 128 + tb0];

    stage(0, 0);                                  // prologue prefetch

    for (int t = 0; t < NITER; t++) {
        // Drains the global_load_lds issued one compute-phase ago (vmcnt(0)
        // inside __syncthreads) and protects buffer reuse. One barrier/iter.
        __syncthreads();
        if (t + 1 < NITER) {
            stage((t + 1) & 1, t + 1);            // in flight across compute(t)
#pragma unroll
            for (int rt = 0; rt < 2; rt++)
#pragma unroll
                for (int r = 0; r < 4; r++)
                    mpn[rt][r] = Mp[(size_t)(q0 + w * 32 + rt * 16 + g * 4 + r) * 128 + tb0 + t + 1];
        }
        const unsigned short* Ks = Ksm[t & 1];
        const unsigned short* Vs = Vsm[t & 1];

#pragma unroll
        for (int rt = 0; rt < 2; rt++) {
            f32x4 sacc[4];
#pragma unroll
            for (int nt = 0; nt < 4; nt++) {
                sacc[nt] = (f32x4){0.f, 0.f, 0.f, 0.f};
#pragma unroll
                for (int ks = 0; ks < 4; ks++) {
                    short8 bf = *reinterpret_cast<const short8*>(
                        &Ks[((nt * 16 + c) * 16 + ((ks * 4 + g) ^ c)) * 8]);
                    sacc[nt] = __builtin_amdgcn_mfma_f32_16x16x32_bf16(qf[rt][ks], bf, sacc[nt], 0, 0, 0);
                }
            }
#pragma unroll
            for (int nt = 0; nt < 4; nt++)
#pragma unroll
                for (int r = 0; r < 4; r++) {
                    bool mv = (mp[rt][r] >> (nt * 16 + c)) & 1ull;
                    float p = mv ? 0.f : __expf(sacc[nt][r] * (1.0f / 128.0f));
                    int row = g * 4 + r;
                    Pw[(row * 8 + ((nt * 2 + (c >> 3)) ^ (row & 7))) * 8 + (c & 7)] = f2bf(p);
                }
            // P written and read by the same wave only (lgkmcnt ordering).
#pragma unroll
            for (int ks2 = 0; ks2 < 2; ks2++) {
                short8 af = *reinterpret_cast<const short8*>(
                    &Pw[(c * 8 + ((ks2 * 4 + g) ^ (c & 7))) * 8]);
                accL[rt] = __builtin_amdgcn_mfma_f32_16x16x32_bf16(af, ones, accL[rt], 0, 0, 0);
#pragma unroll
                for (int dt = 0; dt < 8; dt++) {
                    short8 bfv = *reinterpret_cast<const short8*>(
                        &Vs[((dt * 16 + c) * 8 + ((ks2 * 4 + g) ^ (c & 7))) * 8]);
                    accO[rt][dt] = __builtin_amdgcn_mfma_f32_16x16x32_bf16(af, bfv, accO[rt][dt], 0, 0, 0);
                }
            }
        }
#pragma unroll
        for (int rt = 0; rt < 2; rt++)
#pragma unroll
            for (int r = 0; r < 4; r++) mp[rt][r] = mpn[rt][r];
    }

    // Fragment-contiguous Opart: per (rt,r) a wave writes 1 KB contiguous.
    // elem offset within wave-chunk(4096): (((rt*4+r)*4+g)*16+c)*8 + dt
    _Float16* Ob = Opart + ((size_t)split * 64 + qb) * (128 * DDIM) + (size_t)w * 4096;
#pragma unroll
    for (int rt = 0; rt < 2; rt++)
#pragma unroll
        for (int r = 0; r < 4; r++) {
            unsigned short o[8];
#pragma unroll
            for (int dt = 0; dt < 8; dt++) o[dt] = f2h(accO[rt][dt][r]);
            *reinterpret_cast<uint4*>(Ob + ((((rt * 4 + r) * 4 + g) * 16 + c) * 8)) =
                *reinterpret_cast<uint4*>(o);
        }
    if (c == 0) {
#pragma unroll
        for (int rt = 0; rt < 2; rt++)
#pragma unroll
            for (int r = 0; r < 4; r++)
                lpart[(size_t)split * NTOK + q0 + w * 32 + rt * 16 + g * 4 + r] = accL[rt][r];
    }
}

// ---------------------------------------------------------------------------
// Kernel 4: combine (inverts the fragment-contiguous Opart layout).
// ---------------------------------------------------------------------------
__global__ __launch_bounds__(256) void combine(
    const _Float16* __restrict__ Opart, const float* __restrict__ lpart,
    float* __restrict__ out)
{
    int idx = blockIdx.x * 256 + threadIdx.x;     // (row, d)
    int row = idx >> 7, d = idx & 127;
    int qb = row >> 7, win = row & 127;
    int w = win >> 5, rt = (win >> 4) & 1, g = (win >> 2) & 3, r = win & 3;
    int nt = d >> 4, c = d & 15;
    size_t off = (size_t)qb * (128 * DDIM) + (size_t)w * 4096
               + ((((rt * 4 + r) * 4 + g) * 16 + c) * 8) + nt;
    const size_t S = (size_t)NTOK * DDIM;
    float den = 0.f, num = 0.f;
#pragma unroll
    for (int s = 0; s < NSPLIT; s++) {
        den += lpart[(size_t)s * NTOK + row];
        num += (float)Opart[(size_t)s * S + off];
    }
    out[idx] = (den > 0.f) ? (num / den) : 0.f;
}

// ---------------------------------------------------------------------------
extern "C" void kernel_launch(void* const* d_in, const int* in_sizes, int n_in,
                              void* d_out, int out_size, void* d_ws, size_t ws_size,
                              hipStream_t stream)
{
    const void* X = d_in[0]; const void* mask = d_in[1]; const void* W = d_in[2];
    {
        const void* x_ = nullptr; const void* m_ = nullptr; const void* w_ = nullptr;
        for (int i = 0; i < n_in; i++) {
            if (in_sizes[i] == 16777216) x_ = d_in[i];
            else if (in_sizes[i] == 67108864) m_ = d_in[i];
            else if (in_sizes[i] == 786432) w_ = d_in[i];
        }
        if (x_ && m_ && w_) { X = x_; mask = m_; W = w_; }
    }
    float* out = (float*)d_out;                 // fp32 [8192][128]

    char* ws = (char*)d_ws;
    unsigned short* Qb  = (unsigned short*)(ws);                    // 0..2 MB
    unsigned short* Kb  = (unsigned short*)(ws + (2ull << 20));     // 2..4
    unsigned short* VT  = (unsigned short*)(ws + (4ull << 20));     // 4..6
    unsigned long long* Mpk = (unsigned long long*)(ws + (6ull << 20)); // 6..14
    _Float16*       Opart = (_Float16*)(ws + (14ull << 20));        // 14..30
    unsigned short* Wbf = (unsigned short*)(ws + (14ull << 20));    // alias (dead before attn)
    unsigned short* Vb  = (unsigned short*)(ws + (14ull << 20) + (1536ull << 10)); // dead after vtrans
    float*          lpart = (float*)(ws + (30ull << 20));           // 30..30.25
    int*            flags = (int*)(ws + (30ull << 20) + (512ull << 10));

    detect_kernel<<<1, 64, 0, stream>>>((const unsigned int*)X, (const unsigned int*)mask, flags);
    conv_w<<<dim3(384), 256, 0, stream>>>(W, flags, Wbf);
    mask_pack<<<dim3(2048), 256, 0, stream>>>(mask, flags, (unsigned char*)Mpk);
    qkv_gemm<<<dim3(256, 3), 256, 0, stream>>>(X, Wbf, flags, Qb, Kb, Vb);
    vtrans<<<dim3(256, 4), 256, 0, stream>>>(Vb, VT);
    attn_part<<<dim3(NSPLIT, 64), 256, 0, stream>>>(Qb, Kb, VT, Mpk, Opart, lpart);
    combine<<<dim3(4096), 256, 0, stream>>>(Opart, lpart, out);
}

// Round 2
// 535.470 us; speedup vs baseline: 1.0155x; 1.0114x over previous
//
#include <hip/hip_runtime.h>
#include <hip/hip_bf16.h>

typedef __attribute__((ext_vector_type(8))) short short8;
typedef __attribute__((ext_vector_type(4))) float f32x4;

#define NTOK 8192
#define HCH  2048
#define DDIM 128
#define NSPLIT 8
#define KPS   (NTOK / NSPLIT)     // 1024
#define NITER (KPS / 64)          // 16

__device__ __forceinline__ unsigned short f2bf(float f) {
    __hip_bfloat16 h = __float2bfloat16(f);
    return *reinterpret_cast<unsigned short*>(&h);
}
__device__ __forceinline__ unsigned short f2h(float f) {
    _Float16 h = (_Float16)f;
    return *reinterpret_cast<unsigned short*>(&h);
}

// Direct global->LDS (width 16). LDS dest must be linear in lane order
// (wave-uniform base + lane*16); swizzle is applied on the SOURCE address.
__device__ __forceinline__ void gload_lds16(const void* g, void* l) {
    __builtin_amdgcn_global_load_lds(
        reinterpret_cast<const __attribute__((address_space(1))) unsigned int*>(
            reinterpret_cast<uintptr_t>(g)),
        reinterpret_cast<__attribute__((address_space(3))) unsigned int*>(
            reinterpret_cast<uintptr_t>(l)),
        16, 0, 0);
}

// ---------------------------------------------------------------------------
// Kernel 0: runtime dtype detection (one wave, parallel).
// ---------------------------------------------------------------------------
__global__ void detect_kernel(const unsigned int* __restrict__ X,
                              const unsigned int* __restrict__ M,
                              int* __restrict__ flags)
{
    const int lane = threadIdx.x & 63;
    unsigned int e = (X[lane] >> 7) & 0xFF;
    unsigned long long hb = __ballot(e >= 110 && e <= 140);

    bool w_ok = true, h_ok = true, b_ok = true;
#pragma unroll
    for (int i = 0; i < 16; i++) {
        unsigned int u = M[lane + 64 * i];
        if (!(u == 0u || u == 1u || u == 0x3F800000u)) w_ok = false;
        unsigned int h0 = u & 0xFFFFu, h1 = u >> 16;
        bool o0 = (h0 == 0u || h0 == 0x3F80u || h0 == 0x3C00u || h0 == 1u);
        bool o1 = (h1 == 0u || h1 == 0x3F80u || h1 == 0x3C00u || h1 == 1u);
        if (!(o0 && o1)) h_ok = false;
        unsigned int b0 = u & 0xFF, b1 = (u >> 8) & 0xFF,
                     b2 = (u >> 16) & 0xFF, b3 = u >> 24;
        if (b0 > 1u || b1 > 1u || b2 > 1u || b3 > 1u) b_ok = false;
    }
    bool allw = __all(w_ok), allh = __all(h_ok), allb = __all(b_ok);
    if (lane == 0) {
        flags[0] = (__popcll(hb) < 32) ? 1 : 0;
        flags[1] = allw ? 0 : (allb ? 1 : (allh ? 2 : 3));
    }
}

// ---------------------------------------------------------------------------
// Kernel 0b: W -> bf16.
// ---------------------------------------------------------------------------
__global__ __launch_bounds__(256) void conv_w(
    const void* __restrict__ Wv, const int* __restrict__ flags,
    unsigned short* __restrict__ Wbf)
{
    int t = blockIdx.x * 256 + threadIdx.x;
    size_t off = (size_t)t * 8;
    if (flags[0] != 0) {
        const float* Wf = (const float*)Wv;
        float4 a = *reinterpret_cast<const float4*>(Wf + off);
        float4 b = *reinterpret_cast<const float4*>(Wf + off + 4);
        unsigned short o[8] = { f2bf(a.x), f2bf(a.y), f2bf(a.z), f2bf(a.w),
                                f2bf(b.x), f2bf(b.y), f2bf(b.z), f2bf(b.w) };
        *reinterpret_cast<uint4*>(Wbf + off) = *reinterpret_cast<uint4*>(o);
    } else {
        *reinterpret_cast<uint4*>(Wbf + off) =
            *reinterpret_cast<const uint4*>((const unsigned short*)Wv + off);
    }
}

// ---------------------------------------------------------------------------
// Kernel 0x: X -> bf16 once (removes per-kk f32 conversion + halves the 3x
// re-read traffic in qkv_gemm).
// ---------------------------------------------------------------------------
__global__ __launch_bounds__(256) void conv_x(
    const void* __restrict__ Xv, const int* __restrict__ flags,
    unsigned short* __restrict__ Xbf)
{
    int t = blockIdx.x * 256 + threadIdx.x;
    size_t off = (size_t)t * 8;
    if (flags[0] != 0) {
        const float* Xf = (const float*)Xv;
        float4 a = *reinterpret_cast<const float4*>(Xf + off);
        float4 b = *reinterpret_cast<const float4*>(Xf + off + 4);
        unsigned short o[8] = { f2bf(a.x), f2bf(a.y), f2bf(a.z), f2bf(a.w),
                                f2bf(b.x), f2bf(b.y), f2bf(b.z), f2bf(b.w) };
        *reinterpret_cast<uint4*>(Xbf + off) = *reinterpret_cast<uint4*>(o);
    } else {
        *reinterpret_cast<uint4*>(Xbf + off) =
            *reinterpret_cast<const uint4*>((const unsigned short*)Xv + off);
    }
}

// ---------------------------------------------------------------------------
// Kernel 0c: mask -> 1 bit/elem (thread per output byte, coalesced).
// ---------------------------------------------------------------------------
__global__ __launch_bounds__(256) void mask_pack(
    const void* __restrict__ maskv, const int* __restrict__ flags,
    unsigned char* __restrict__ Mp)
{
    const int mmode = flags[1];
    const int NB = NTOK * (NTOK / 8);
    int t0 = blockIdx.x * 256 + threadIdx.x;
    for (int b = t0; b < NB; b += 2048 * 256) {
        unsigned int byte = 0;
        if (mmode == 0) {
            const uint4* p = reinterpret_cast<const uint4*>(
                (const unsigned int*)maskv + (size_t)b * 8);
            uint4 a = p[0], c = p[1];
            byte = (a.x != 0u) | ((a.y != 0u) << 1) | ((a.z != 0u) << 2) | ((a.w != 0u) << 3)
                 | ((c.x != 0u) << 4) | ((c.y != 0u) << 5) | ((c.z != 0u) << 6) | ((c.w != 0u) << 7);
        } else if (mmode == 1) {
            unsigned long long v = *reinterpret_cast<const unsigned long long*>(
                (const unsigned char*)maskv + (size_t)b * 8);
#pragma unroll
            for (int k = 0; k < 8; k++)
                byte |= (((v >> (8 * k)) & 0xFFull) != 0ull) << k;
        } else if (mmode == 2) {
            uint4 a = *reinterpret_cast<const uint4*>(
                (const unsigned short*)maskv + (size_t)b * 8);
            byte = ((a.x & 0xFFFFu) != 0u) | ((a.x >> 16 != 0u) << 1)
                 | (((a.y & 0xFFFFu) != 0u) << 2) | ((a.y >> 16 != 0u) << 3)
                 | (((a.z & 0xFFFFu) != 0u) << 4) | ((a.z >> 16 != 0u) << 5)
                 | (((a.w & 0xFFFFu) != 0u) << 6) | ((a.w >> 16 != 0u) << 7);
        } else {
            byte = ((const unsigned char*)maskv)[b];
        }
        Mp[b] = (unsigned char)byte;
    }
}

// ---------------------------------------------------------------------------
// Kernel 1: QKV projection v2 — bf16 X input; both tiles staged via
// global_load_lds (linear LDS dest + inverse-swizzled SOURCE; effective LDS
// layout identical to the old ds_write path: slot s of row n holds chunk
// s^(n&7), so the read side is byte-identical).
// ---------------------------------------------------------------------------
__global__ __launch_bounds__(256) void qkv_gemm(
    const unsigned short* __restrict__ Xbf, const unsigned short* __restrict__ Wbf,
    unsigned short* __restrict__ Qb, unsigned short* __restrict__ Kb,
    unsigned short* __restrict__ Vb)
{
    __shared__ unsigned short Wsm[128 * 64];
    __shared__ unsigned short Xsm[32 * 64];
    const int tid  = threadIdx.x;
    const int lane = tid & 63, w = tid >> 6;
    const int c = lane & 15, g = lane >> 4;
    const int q0 = blockIdx.x * 32;
    const int n0 = blockIdx.y * 128;

    f32x4 acc[4];
#pragma unroll
    for (int i = 0; i < 4; i++) acc[i] = (f32x4){0.f, 0.f, 0.f, 0.f};

    const int xrow = tid >> 3, xc8 = tid & 7;
    const int arow = (w & 1) * 16 + c;

    for (int kk = 0; kk < HCH; kk += 64) {
        __syncthreads();                         // prev-tile reads done
#pragma unroll
        for (int i = 0; i < 4; i++) {            // W tile [128][64]
            int cid = tid + 256 * i;
            int n = cid >> 3, c8 = cid & 7;
            gload_lds16(Wbf + (size_t)(n0 + n) * HCH + kk + ((c8 ^ (n & 7)) * 8),
                        &Wsm[cid * 8]);
        }
        gload_lds16(Xbf + (size_t)(q0 + xrow) * HCH + kk + ((xc8 ^ (xrow & 7)) * 8),
                    &Xsm[tid * 8]);              // X tile [32][64]
        __syncthreads();                         // drains vmcnt (compiler waitcnt)
#pragma unroll
        for (int ks = 0; ks < 2; ks++) {
            short8 af = *reinterpret_cast<const short8*>(
                &Xsm[(arow * 8 + ((ks * 4 + g) ^ (c & 7))) * 8]);
#pragma unroll
            for (int nt = 0; nt < 4; nt++) {
                int n = (w >> 1) * 64 + nt * 16 + c;
                short8 bf = *reinterpret_cast<const short8*>(
                    &Wsm[(n * 8 + ((ks * 4 + g) ^ (c & 7))) * 8]);
                acc[nt] = __builtin_amdgcn_mfma_f32_16x16x32_bf16(af, bf, acc[nt], 0, 0, 0);
            }
        }
    }
    unsigned short* dst = (blockIdx.y == 0) ? Qb : (blockIdx.y == 1) ? Kb : Vb;
#pragma unroll
    for (int nt = 0; nt < 4; nt++) {
        int n = (w >> 1) * 64 + nt * 16 + c;
#pragma unroll
        for (int r = 0; r < 4; r++) {
            int rr = q0 + (w & 1) * 16 + g * 4 + r;
            dst[(size_t)rr * DDIM + n] = f2bf(acc[nt][r]);
        }
    }
}

// ---------------------------------------------------------------------------
// Kernel 2: V -> VT (unchanged).
// ---------------------------------------------------------------------------
__global__ __launch_bounds__(256) void vtrans(
    const unsigned short* __restrict__ V, unsigned short* __restrict__ VT)
{
    __shared__ unsigned short T[32 * 33];
    const int t = threadIdx.x;
    const int k0 = blockIdx.x * 32, d0 = blockIdx.y * 32;
    {
        int key = t >> 3, dq = (t & 7) * 4;
        ushort4 v = *reinterpret_cast<const ushort4*>(V + (size_t)(k0 + key) * DDIM + d0 + dq);
        T[(dq + 0) * 33 + key] = v.x;
        T[(dq + 1) * 33 + key] = v.y;
        T[(dq + 2) * 33 + key] = v.z;
        T[(dq + 3) * 33 + key] = v.w;
    }
    __syncthreads();
    {
        int d = t >> 3, kq = (t & 7) * 4;
        ushort4 o;
        o.x = T[d * 33 + kq + 0]; o.y = T[d * 33 + kq + 1];
        o.z = T[d * 33 + kq + 2]; o.w = T[d * 33 + kq + 3];
        *reinterpret_cast<ushort4*>(VT + (size_t)(d0 + d) * NTOK + k0 + kq) = o;
    }
}

// ---------------------------------------------------------------------------
// Kernel 3: flash partials v6 (unchanged from round 1 — measured neutral,
// kept for the single-barrier structure).
// ---------------------------------------------------------------------------
__global__ __launch_bounds__(256) void attn_part(
    const unsigned short* __restrict__ Qb, const unsigned short* __restrict__ Kb,
    const unsigned short* __restrict__ VT, const unsigned long long* __restrict__ Mp,
    _Float16* __restrict__ Opart, float* __restrict__ lpart)
{
    __shared__ unsigned short Ksm[2][64 * 128];   // 2 x 16 KB
    __shared__ unsigned short Vsm[2][128 * 64];   // 2 x 16 KB
    __shared__ unsigned short Psm[4 * 16 * 64];   // 8 KB  (72 KB total -> 2 blk/CU)
    const int tid  = threadIdx.x;
    const int lane = tid & 63, w = tid >> 6;
    const int c = lane & 15, g = lane >> 4;
    const int split = blockIdx.x;              // 0..7
    const int qb    = blockIdx.y;              // 0..63
    const int q0 = qb * 128;
    const int kbase = split * KPS;
    const int tb0 = kbase >> 6;
    unsigned short* Pw = &Psm[w * 16 * 64];

    auto stage = [&](int b, int tt) {
        const int k0s = kbase + tt * 64;
#pragma unroll
        for (int i = 0; i < 4; i++) {
            int cid = tid + 256 * i;
            int rowk = cid >> 4, c16 = cid & 15;
            gload_lds16(Kb + (size_t)(k0s + rowk) * DDIM + ((c16 ^ (rowk & 15)) * 8),
                        &Ksm[b][cid * 8]);
        }
#pragma unroll
        for (int i = 0; i < 4; i++) {
            int cid = tid + 256 * i;
            int d = cid >> 3, c8 = cid & 7;
            gload_lds16(VT + (size_t)d * NTOK + k0s + ((c8 ^ (d & 7)) * 8),
                        &Vsm[b][cid * 8]);
        }
    };

    short8 qf[2][4];
#pragma unroll
    for (int rt = 0; rt < 2; rt++)
#pragma unroll
        for (int ks = 0; ks < 4; ks++)
            qf[rt][ks] = *reinterpret_cast<const short8*>(
                Qb + (size_t)(q0 + w * 32 + rt * 16 + c) * DDIM + ks * 32 + g * 8);

    short8 ones;
#pragma unroll
    for (int i = 0; i < 8; i++) ones[i] = (short)0x3F80;   // bf16 1.0

    f32x4 accO[2][8];
#pragma unroll
    for (int rt = 0; rt < 2; rt++)
#pragma unroll
        for (int i = 0; i < 8; i++) accO[rt][i] = (f32x4){0.f, 0.f, 0.f, 0.f};
    f32x4 accL[2] = {(f32x4){0.f,0.f,0.f,0.f}, (f32x4){0.f,0.f,0.f,0.f}};

    unsigned long long mp[2][4], mpn[2][4];
#pragma unroll
    for (int rt = 0; rt < 2; rt++)
#pragma unroll
        for (int r = 0; r < 4; r++)
            mp[rt][r] = Mp[(size_t)(q0 + w * 32 + rt * 16 + g * 4 + r) * 128 + tb0];

    stage(0, 0);                                  // prologue prefetch

    for (int t = 0; t < NITER; t++) {
        __syncthreads();                          // drains staged loads, 1/iter
        if (t + 1 < NITER) {
            stage((t + 1) & 1, t + 1);            // in flight across compute(t)
#pragma unroll
            for (int rt = 0; rt < 2; rt++)
#pragma unroll
                for (int r = 0; r < 4; r++)
                    mpn[rt][r] = Mp[(size_t)(q0 + w * 32 + rt * 16 + g * 4 + r) * 128 + tb0 + t + 1];
        }
        const unsigned short* Ks = Ksm[t & 1];
        const unsigned short* Vs = Vsm[t & 1];

#pragma unroll
        for (int rt = 0; rt < 2; rt++) {
            f32x4 sacc[4];
#pragma unroll
            for (int nt = 0; nt < 4; nt++) {
                sacc[nt] = (f32x4){0.f, 0.f, 0.f, 0.f};
#pragma unroll
                for (int ks = 0; ks < 4; ks++) {
                    short8 bf = *reinterpret_cast<const short8*>(
                        &Ks[((nt * 16 + c) * 16 + ((ks * 4 + g) ^ c)) * 8]);
                    sacc[nt] = __builtin_amdgcn_mfma_f32_16x16x32_bf16(qf[rt][ks], bf, sacc[nt], 0, 0, 0);
                }
            }
#pragma unroll
            for (int nt = 0; nt < 4; nt++)
#pragma unroll
                for (int r = 0; r < 4; r++) {
                    bool mv = (mp[rt][r] >> (nt * 16 + c)) & 1ull;
                    float p = mv ? 0.f : __expf(sacc[nt][r] * (1.0f / 128.0f));
                    int row = g * 4 + r;
                    Pw[(row * 8 + ((nt * 2 + (c >> 3)) ^ (row & 7))) * 8 + (c & 7)] = f2bf(p);
                }
#pragma unroll
            for (int ks2 = 0; ks2 < 2; ks2++) {
                short8 af = *reinterpret_cast<const short8*>(
                    &Pw[(c * 8 + ((ks2 * 4 + g) ^ (c & 7))) * 8]);
                accL[rt] = __builtin_amdgcn_mfma_f32_16x16x32_bf16(af, ones, accL[rt], 0, 0, 0);
#pragma unroll
                for (int dt = 0; dt < 8; dt++) {
                    short8 bfv = *reinterpret_cast<const short8*>(
                        &Vs[((dt * 16 + c) * 8 + ((ks2 * 4 + g) ^ (c & 7))) * 8]);
                    accO[rt][dt] = __builtin_amdgcn_mfma_f32_16x16x32_bf16(af, bfv, accO[rt][dt], 0, 0, 0);
                }
            }
        }
#pragma unroll
        for (int rt = 0; rt < 2; rt++)
#pragma unroll
            for (int r = 0; r < 4; r++) mp[rt][r] = mpn[rt][r];
    }

    _Float16* Ob = Opart + ((size_t)split * 64 + qb) * (128 * DDIM) + (size_t)w * 4096;
#pragma unroll
    for (int rt = 0; rt < 2; rt++)
#pragma unroll
        for (int r = 0; r < 4; r++) {
            unsigned short o[8];
#pragma unroll
            for (int dt = 0; dt < 8; dt++) o[dt] = f2h(accO[rt][dt][r]);
            *reinterpret_cast<uint4*>(Ob + ((((rt * 4 + r) * 4 + g) * 16 + c) * 8)) =
                *reinterpret_cast<uint4*>(o);
        }
    if (c == 0) {
#pragma unroll
        for (int rt = 0; rt < 2; rt++)
#pragma unroll
            for (int r = 0; r < 4; r++)
                lpart[(size_t)split * NTOK + q0 + w * 32 + rt * 16 + g * 4 + r] = accL[rt][r];
    }
}

// ---------------------------------------------------------------------------
// Kernel 4: combine v2 — one thread per 8-elem fragment chunk: 16-B coalesced
// reads per split (was eight 2-B strided reads = 8x BW waste).
// ---------------------------------------------------------------------------
__global__ __launch_bounds__(256) void combine(
    const _Float16* __restrict__ Opart, const float* __restrict__ lpart,
    float* __restrict__ out)
{
    int cid = blockIdx.x * 256 + threadIdx.x;     // 131072 chunks
    int c = cid & 15, g = (cid >> 4) & 3, r = (cid >> 6) & 3;
    int rt = (cid >> 8) & 1, w = (cid >> 9) & 3, qb = cid >> 11;
    int row = qb * 128 + w * 32 + rt * 16 + g * 4 + r;
    size_t base = (size_t)qb * (128 * DDIM) + (size_t)w * 4096
                + ((((rt * 4 + r) * 4 + g) * 16 + c) * 8);
    const size_t S = (size_t)NTOK * DDIM;
    float den = 0.f;
    float num[8] = {0.f, 0.f, 0.f, 0.f, 0.f, 0.f, 0.f, 0.f};
#pragma unroll
    for (int s = 0; s < NSPLIT; s++) {
        den += lpart[(size_t)s * NTOK + row];
        uint4 v = *reinterpret_cast<const uint4*>(Opart + (size_t)s * S + base);
        const _Float16* h = reinterpret_cast<const _Float16*>(&v);
#pragma unroll
        for (int dt = 0; dt < 8; dt++) num[dt] += (float)h[dt];
    }
    float inv = (den > 0.f) ? (1.f / den) : 0.f;
#pragma unroll
    for (int dt = 0; dt < 8; dt++)
        out[(size_t)row * DDIM + dt * 16 + c] = num[dt] * inv;
}

// ---------------------------------------------------------------------------
extern "C" void kernel_launch(void* const* d_in, const int* in_sizes, int n_in,
                              void* d_out, int out_size, void* d_ws, size_t ws_size,
                              hipStream_t stream)
{
    const void* X = d_in[0]; const void* mask = d_in[1]; const void* W = d_in[2];
    {
        const void* x_ = nullptr; const void* m_ = nullptr; const void* w_ = nullptr;
        for (int i = 0; i < n_in; i++) {
            if (in_sizes[i] == 16777216) x_ = d_in[i];
            else if (in_sizes[i] == 67108864) m_ = d_in[i];
            else if (in_sizes[i] == 786432) w_ = d_in[i];
        }
        if (x_ && m_ && w_) { X = x_; mask = m_; W = w_; }
    }
    float* out = (float*)d_out;                 // fp32 [8192][128]

    char* ws = (char*)d_ws;
    unsigned short* Qb  = (unsigned short*)(ws);                    // 0..2 MB
    unsigned short* Kb  = (unsigned short*)(ws + (2ull << 20));     // 2..4
    unsigned short* VT  = (unsigned short*)(ws + (4ull << 20));     // 4..6
    unsigned long long* Mpk = (unsigned long long*)(ws + (6ull << 20)); // 6..14
    _Float16*       Opart = (_Float16*)(ws + (14ull << 20));        // 14..30
    unsigned short* Wbf = (unsigned short*)(ws + (14ull << 20));    // alias (dead before attn)
    unsigned short* Vb  = (unsigned short*)(ws + (14ull << 20) + (1536ull << 10)); // dead after vtrans
    float*          lpart = (float*)(ws + (30ull << 20));           // 30..30.25
    int*            flags = (int*)(ws + (30ull << 20) + (512ull << 10));
    unsigned short* Xbf = (unsigned short*)(ws + (32ull << 20));    // 32..64 MB (dead after qkv)

    detect_kernel<<<1, 64, 0, stream>>>((const unsigned int*)X, (const unsigned int*)mask, flags);
    conv_w<<<dim3(384), 256, 0, stream>>>(W, flags, Wbf);
    conv_x<<<dim3(8192), 256, 0, stream>>>(X, flags, Xbf);
    mask_pack<<<dim3(2048), 256, 0, stream>>>(mask, flags, (unsigned char*)Mpk);
    qkv_gemm<<<dim3(256, 3), 256, 0, stream>>>(Xbf, Wbf, Qb, Kb, Vb);
    vtrans<<<dim3(256, 4), 256, 0, stream>>>(Vb, VT);
    attn_part<<<dim3(NSPLIT, 64), 256, 0, stream>>>(Qb, Kb, VT, Mpk, Opart, lpart);
    combine<<<dim3(4096 / 8), 256, 0, stream>>>(Opart, lpart, out);
}

// Round 4
// 525.103 us; speedup vs baseline: 1.0355x; 1.0197x over previous
//
#include <hip/hip_runtime.h>
#include <hip/hip_bf16.h>

typedef __attribute__((ext_vector_type(8))) short short8;
typedef __attribute__((ext_vector_type(4))) float f32x4;
typedef __attribute__((ext_vector_type(16))) float f32x16;
typedef __attribute__((ext_vector_type(2))) unsigned int uint2v;

#define NTOK 8192
#define HCH  2048
#define DDIM 128
#define NSPLIT 8
#define KPS   (NTOK / NSPLIT)     // 1024
#define NITER (KPS / 64)          // 16

__device__ __forceinline__ unsigned short f2bf(float f) {
    __hip_bfloat16 h = __float2bfloat16(f);
    return *reinterpret_cast<unsigned short*>(&h);
}
__device__ __forceinline__ unsigned short f2h(float f) {
    _Float16 h = (_Float16)f;
    return *reinterpret_cast<unsigned short*>(&h);
}

// Direct global->LDS (width 16). LDS dest must be linear in lane order
// (wave-uniform base + lane*16); swizzle is applied on the SOURCE address.
__device__ __forceinline__ void gload_lds16(const void* g, void* l) {
    __builtin_amdgcn_global_load_lds(
        reinterpret_cast<const __attribute__((address_space(1))) unsigned int*>(
            reinterpret_cast<uintptr_t>(g)),
        reinterpret_cast<__attribute__((address_space(3))) unsigned int*>(
            reinterpret_cast<uintptr_t>(l)),
        16, 0, 0);
}

// ---------------------------------------------------------------------------
// Kernel 0: runtime dtype detection (one wave, parallel).
// ---------------------------------------------------------------------------
__global__ void detect_kernel(const unsigned int* __restrict__ X,
                              const unsigned int* __restrict__ M,
                              int* __restrict__ flags)
{
    const int lane = threadIdx.x & 63;
    unsigned int e = (X[lane] >> 7) & 0xFF;
    unsigned long long hb = __ballot(e >= 110 && e <= 140);

    bool w_ok = true, h_ok = true, b_ok = true;
#pragma unroll
    for (int i = 0; i < 16; i++) {
        unsigned int u = M[lane + 64 * i];
        if (!(u == 0u || u == 1u || u == 0x3F800000u)) w_ok = false;
        unsigned int h0 = u & 0xFFFFu, h1 = u >> 16;
        bool o0 = (h0 == 0u || h0 == 0x3F80u || h0 == 0x3C00u || h0 == 1u);
        bool o1 = (h1 == 0u || h1 == 0x3F80u || h1 == 0x3C00u || h1 == 1u);
        if (!(o0 && o1)) h_ok = false;
        unsigned int b0 = u & 0xFF, b1 = (u >> 8) & 0xFF,
                     b2 = (u >> 16) & 0xFF, b3 = u >> 24;
        if (b0 > 1u || b1 > 1u || b2 > 1u || b3 > 1u) b_ok = false;
    }
    bool allw = __all(w_ok), allh = __all(h_ok), allb = __all(b_ok);
    if (lane == 0) {
        flags[0] = (__popcll(hb) < 32) ? 1 : 0;
        flags[1] = allw ? 0 : (allb ? 1 : (allh ? 2 : 3));
    }
}

// ---------------------------------------------------------------------------
// Kernel 0b: W -> bf16.
// ---------------------------------------------------------------------------
__global__ __launch_bounds__(256) void conv_w(
    const void* __restrict__ Wv, const int* __restrict__ flags,
    unsigned short* __restrict__ Wbf)
{
    int t = blockIdx.x * 256 + threadIdx.x;
    size_t off = (size_t)t * 8;
    if (flags[0] != 0) {
        const float* Wf = (const float*)Wv;
        float4 a = *reinterpret_cast<const float4*>(Wf + off);
        float4 b = *reinterpret_cast<const float4*>(Wf + off + 4);
        unsigned short o[8] = { f2bf(a.x), f2bf(a.y), f2bf(a.z), f2bf(a.w),
                                f2bf(b.x), f2bf(b.y), f2bf(b.z), f2bf(b.w) };
        *reinterpret_cast<uint4*>(Wbf + off) = *reinterpret_cast<uint4*>(o);
    } else {
        *reinterpret_cast<uint4*>(Wbf + off) =
            *reinterpret_cast<const uint4*>((const unsigned short*)Wv + off);
    }
}

// ---------------------------------------------------------------------------
// Kernel 0x: X -> bf16 once.
// ---------------------------------------------------------------------------
__global__ __launch_bounds__(256) void conv_x(
    const void* __restrict__ Xv, const int* __restrict__ flags,
    unsigned short* __restrict__ Xbf)
{
    int t = blockIdx.x * 256 + threadIdx.x;
    size_t off = (size_t)t * 8;
    if (flags[0] != 0) {
        const float* Xf = (const float*)Xv;
        float4 a = *reinterpret_cast<const float4*>(Xf + off);
        float4 b = *reinterpret_cast<const float4*>(Xf + off + 4);
        unsigned short o[8] = { f2bf(a.x), f2bf(a.y), f2bf(a.z), f2bf(a.w),
                                f2bf(b.x), f2bf(b.y), f2bf(b.z), f2bf(b.w) };
        *reinterpret_cast<uint4*>(Xbf + off) = *reinterpret_cast<uint4*>(o);
    } else {
        *reinterpret_cast<uint4*>(Xbf + off) =
            *reinterpret_cast<const uint4*>((const unsigned short*)Xv + off);
    }
}

// ---------------------------------------------------------------------------
// Kernel 0c: mask -> 1 bit/elem (thread per output byte, coalesced).
// ---------------------------------------------------------------------------
__global__ __launch_bounds__(256) void mask_pack(
    const void* __restrict__ maskv, const int* __restrict__ flags,
    unsigned char* __restrict__ Mp)
{
    const int mmode = flags[1];
    const int NB = NTOK * (NTOK / 8);
    int t0 = blockIdx.x * 256 + threadIdx.x;
    for (int b = t0; b < NB; b += 2048 * 256) {
        unsigned int byte = 0;
        if (mmode == 0) {
            const uint4* p = reinterpret_cast<const uint4*>(
                (const unsigned int*)maskv + (size_t)b * 8);
            uint4 a = p[0], c = p[1];
            byte = (a.x != 0u) | ((a.y != 0u) << 1) | ((a.z != 0u) << 2) | ((a.w != 0u) << 3)
                 | ((c.x != 0u) << 4) | ((c.y != 0u) << 5) | ((c.z != 0u) << 6) | ((c.w != 0u) << 7);
        } else if (mmode == 1) {
            unsigned long long v = *reinterpret_cast<const unsigned long long*>(
                (const unsigned char*)maskv + (size_t)b * 8);
#pragma unroll
            for (int k = 0; k < 8; k++)
                byte |= (((v >> (8 * k)) & 0xFFull) != 0ull) << k;
        } else if (mmode == 2) {
            uint4 a = *reinterpret_cast<const uint4*>(
                (const unsigned short*)maskv + (size_t)b * 8);
            byte = ((a.x & 0xFFFFu) != 0u) | ((a.x >> 16 != 0u) << 1)
                 | (((a.y & 0xFFFFu) != 0u) << 2) | ((a.y >> 16 != 0u) << 3)
                 | (((a.z & 0xFFFFu) != 0u) << 4) | ((a.z >> 16 != 0u) << 5)
                 | (((a.w & 0xFFFFu) != 0u) << 6) | ((a.w >> 16 != 0u) << 7);
        } else {
            byte = ((const unsigned char*)maskv)[b];
        }
        Mp[b] = (unsigned char)byte;
    }
}

// ---------------------------------------------------------------------------
// Kernel 1: QKV projection (unchanged from round 2).
// ---------------------------------------------------------------------------
__global__ __launch_bounds__(256) void qkv_gemm(
    const unsigned short* __restrict__ Xbf, const unsigned short* __restrict__ Wbf,
    unsigned short* __restrict__ Qb, unsigned short* __restrict__ Kb,
    unsigned short* __restrict__ Vb)
{
    __shared__ unsigned short Wsm[128 * 64];
    __shared__ unsigned short Xsm[32 * 64];
    const int tid  = threadIdx.x;
    const int lane = tid & 63, w = tid >> 6;
    const int c = lane & 15, g = lane >> 4;
    const int q0 = blockIdx.x * 32;
    const int n0 = blockIdx.y * 128;

    f32x4 acc[4];
#pragma unroll
    for (int i = 0; i < 4; i++) acc[i] = (f32x4){0.f, 0.f, 0.f, 0.f};

    const int xrow = tid >> 3, xc8 = tid & 7;
    const int arow = (w & 1) * 16 + c;

    for (int kk = 0; kk < HCH; kk += 64) {
        __syncthreads();
#pragma unroll
        for (int i = 0; i < 4; i++) {
            int cid = tid + 256 * i;
            int n = cid >> 3, c8 = cid & 7;
            gload_lds16(Wbf + (size_t)(n0 + n) * HCH + kk + ((c8 ^ (n & 7)) * 8),
                        &Wsm[cid * 8]);
        }
        gload_lds16(Xbf + (size_t)(q0 + xrow) * HCH + kk + ((xc8 ^ (xrow & 7)) * 8),
                    &Xsm[tid * 8]);
        __syncthreads();
#pragma unroll
        for (int ks = 0; ks < 2; ks++) {
            short8 af = *reinterpret_cast<const short8*>(
                &Xsm[(arow * 8 + ((ks * 4 + g) ^ (c & 7))) * 8]);
#pragma unroll
            for (int nt = 0; nt < 4; nt++) {
                int n = (w >> 1) * 64 + nt * 16 + c;
                short8 bf = *reinterpret_cast<const short8*>(
                    &Wsm[(n * 8 + ((ks * 4 + g) ^ (c & 7))) * 8]);
                acc[nt] = __builtin_amdgcn_mfma_f32_16x16x32_bf16(af, bf, acc[nt], 0, 0, 0);
            }
        }
    }
    unsigned short* dst = (blockIdx.y == 0) ? Qb : (blockIdx.y == 1) ? Kb : Vb;
#pragma unroll
    for (int nt = 0; nt < 4; nt++) {
        int n = (w >> 1) * 64 + nt * 16 + c;
#pragma unroll
        for (int r = 0; r < 4; r++) {
            int rr = q0 + (w & 1) * 16 + g * 4 + r;
            dst[(size_t)rr * DDIM + n] = f2bf(acc[nt][r]);
        }
    }
}

// ---------------------------------------------------------------------------
// Kernel 2: V -> VT (unchanged).
// ---------------------------------------------------------------------------
__global__ __launch_bounds__(256) void vtrans(
    const unsigned short* __restrict__ V, unsigned short* __restrict__ VT)
{
    __shared__ unsigned short T[32 * 33];
    const int t = threadIdx.x;
    const int k0 = blockIdx.x * 32, d0 = blockIdx.y * 32;
    {
        int key = t >> 3, dq = (t & 7) * 4;
        ushort4 v = *reinterpret_cast<const ushort4*>(V + (size_t)(k0 + key) * DDIM + d0 + dq);
        T[(dq + 0) * 33 + key] = v.x;
        T[(dq + 1) * 33 + key] = v.y;
        T[(dq + 2) * 33 + key] = v.z;
        T[(dq + 3) * 33 + key] = v.w;
    }
    __syncthreads();
    {
        int d = t >> 3, kq = (t & 7) * 4;
        ushort4 o;
        o.x = T[d * 33 + kq + 0]; o.y = T[d * 33 + kq + 1];
        o.z = T[d * 33 + kq + 2]; o.w = T[d * 33 + kq + 3];
        *reinterpret_cast<ushort4*>(VT + (size_t)(d0 + d) * NTOK + k0 + kq) = o;
    }
}

// ---------------------------------------------------------------------------
// Kernel 3: flash partials v7 — 32x32x16 MFMA, swapped QK^T (mfma(K,Q) so
// each lane owns a P-column for q=lane&31), in-register P via
// v_cvt_pk_bf16_f32 + permlane32_swap (T12). No P LDS round-trip; halves
// the LDS b128 read count. L = per-lane f32 sum + one shfl_xor(32).
// C-layout (m74/m101): col=lane&31, row=(r&3)+8*(r>>2)+4*(lane>>5).
// ---------------------------------------------------------------------------
__global__ __launch_bounds__(256) void attn_part(
    const unsigned short* __restrict__ Qb, const unsigned short* __restrict__ Kb,
    const unsigned short* __restrict__ VT, const unsigned long long* __restrict__ Mp,
    _Float16* __restrict__ Opart, float* __restrict__ lpart)
{
    __shared__ unsigned short Ksm[2][64 * 128];   // 2 x 16 KB, [k][d] chunks swz
    __shared__ unsigned short Vsm[2][128 * 64];   // 2 x 16 KB, [d][k] chunks swz
    const int tid  = threadIdx.x;
    const int lane = tid & 63, w = tid >> 6;
    const int la = lane & 31, hi = lane >> 5;
    const int split = blockIdx.x;              // 0..7
    const int qb    = blockIdx.y;              // 0..63
    const int q0 = qb * 128;
    const int kbase = split * KPS;
    const int tb0 = kbase >> 6;
    const int qrow = q0 + w * 32 + la;         // this lane's q-row

    auto stage = [&](int b, int tt) {
        const int k0s = kbase + tt * 64;
#pragma unroll
        for (int i = 0; i < 4; i++) {
            int cid = tid + 256 * i;
            int rowk = cid >> 4, c16 = cid & 15;
            gload_lds16(Kb + (size_t)(k0s + rowk) * DDIM + ((c16 ^ (rowk & 15)) * 8),
                        &Ksm[b][cid * 8]);
        }
#pragma unroll
        for (int i = 0; i < 4; i++) {
            int cid = tid + 256 * i;
            int d = cid >> 3, c8 = cid & 7;
            gload_lds16(VT + (size_t)d * NTOK + k0s + ((c8 ^ (d & 7)) * 8),
                        &Vsm[b][cid * 8]);
        }
    };

    // Q as B-fragment: lane la = q-col, k(d)=dstep*16 + hi*8 + j
    short8 qf[8];
#pragma unroll
    for (int dstep = 0; dstep < 8; dstep++)
        qf[dstep] = *reinterpret_cast<const short8*>(
            Qb + (size_t)qrow * DDIM + dstep * 16 + hi * 8);

    f32x16 accO[4];
#pragma unroll
    for (int dt = 0; dt < 4; dt++)
#pragma unroll
        for (int r = 0; r < 16; r++) accO[dt][r] = 0.f;
    float Lacc = 0.f;

    unsigned long long mw = Mp[(size_t)qrow * 128 + tb0], mwn = 0;

    stage(0, 0);                                  // prologue prefetch

    for (int t = 0; t < NITER; t++) {
        __syncthreads();                          // drains staged loads, 1/iter
        if (t + 1 < NITER) {
            stage((t + 1) & 1, t + 1);            // in flight across compute(t)
            mwn = Mp[(size_t)qrow * 128 + tb0 + t + 1];
        }
        const unsigned short* Ks = Ksm[t & 1];
        const unsigned short* Vs = Vsm[t & 1];

        // ---- QK^T swapped: S = K-tile x Q^T (two independent MFMA chains)
        f32x16 S0, S1;
#pragma unroll
        for (int r = 0; r < 16; r++) { S0[r] = 0.f; S1[r] = 0.f; }
#pragma unroll
        for (int dstep = 0; dstep < 8; dstep++) {
            int slot = (2 * dstep + hi) ^ (la & 15);
            short8 k0f = *reinterpret_cast<const short8*>(&Ks[(la * 16 + slot) * 8]);
            short8 k1f = *reinterpret_cast<const short8*>(&Ks[((32 + la) * 16 + slot) * 8]);
            S0 = __builtin_amdgcn_mfma_f32_32x32x16_bf16(k0f, qf[dstep], S0, 0, 0, 0);
            S1 = __builtin_amdgcn_mfma_f32_32x32x16_bf16(k1f, qf[dstep], S1, 0, 0, 0);
        }

        // ---- mask + exp + pack to PV A-fragments (in-register, T12)
        const unsigned long long mh = mw >> (4 * hi);
        short8 pa[4];
        auto softpack = [&](const f32x16& S, int kt, short8* paP) {
            float p[16];
#pragma unroll
            for (int r = 0; r < 16; r++) {
                int bit = kt * 32 + (r & 3) + 8 * (r >> 2);
                bool mv = (mh >> bit) & 1ull;
                float e = __expf(S[r] * 0.0078125f);   // exp(x/128)
                p[r] = mv ? 0.f : e;
                Lacc += p[r];
            }
            unsigned int U[4][2];
#pragma unroll
            for (int b = 0; b < 4; b++) {
                asm("v_cvt_pk_bf16_f32 %0, %1, %2"
                    : "=v"(U[b][0]) : "v"(p[4 * b + 0]), "v"(p[4 * b + 1]));
                asm("v_cvt_pk_bf16_f32 %0, %1, %2"
                    : "=v"(U[b][1]) : "v"(p[4 * b + 2]), "v"(p[4 * b + 3]));
            }
#pragma unroll
            for (int h = 0; h < 2; h++) {
                uint2v sA = __builtin_amdgcn_permlane32_swap(U[2 * h][0], U[2 * h + 1][0], false, false);
                uint2v sB = __builtin_amdgcn_permlane32_swap(U[2 * h][1], U[2 * h + 1][1], false, false);
                unsigned int fr[4] = { sA.x, sB.x, sA.y, sB.y };
                paP[h] = *reinterpret_cast<short8*>(fr);
            }
        };
        softpack(S0, 0, &pa[0]);
        softpack(S1, 1, &pa[2]);

        // ---- PV: accO[dt] += P[32q x 16k] * V[16k x 32d]
#pragma unroll
        for (int s = 0; s < 4; s++) {
#pragma unroll
            for (int dt = 0; dt < 4; dt++) {
                int slot = (2 * s + hi) ^ (la & 7);
                short8 vf = *reinterpret_cast<const short8*>(
                    &Vs[((dt * 32 + la) * 8 + slot) * 8]);
                accO[dt] = __builtin_amdgcn_mfma_f32_32x32x16_bf16(pa[s], vf, accO[dt], 0, 0, 0);
            }
        }
        if (t + 1 < NITER) mw = mwn;
    }

    // L: both hi-halves of a q-column hold complementary partial sums.
    Lacc += __shfl_xor(Lacc, 32, 64);

    // Fragment-contiguous Opart: per (dt,b) a wave writes 512 B contiguous.
    // lane holds q = 8b + 4hi + j (j=0..3), d = dt*32 + la.
    _Float16* Ob = Opart + ((size_t)split * 64 + qb) * (128 * DDIM) + (size_t)w * 4096;
#pragma unroll
    for (int dt = 0; dt < 4; dt++)
#pragma unroll
        for (int b = 0; b < 4; b++) {
            unsigned int w0 = (unsigned int)f2h(accO[dt][4 * b + 0])
                            | ((unsigned int)f2h(accO[dt][4 * b + 1]) << 16);
            unsigned int w1 = (unsigned int)f2h(accO[dt][4 * b + 2])
                            | ((unsigned int)f2h(accO[dt][4 * b + 3]) << 16);
            uint2 uv; uv.x = w0; uv.y = w1;
            *reinterpret_cast<uint2*>(Ob + (size_t)((dt * 4 + b) * 64 + lane) * 4) = uv;
        }
    if (hi == 0)
        lpart[(size_t)split * NTOK + q0 + w * 32 + la] = Lacc;
}

// ---------------------------------------------------------------------------
// Kernel 4: combine v3 (inverts the v7 fragment layout; 8-B reads/split).
// ---------------------------------------------------------------------------
__global__ __launch_bounds__(256) void combine(
    const _Float16* __restrict__ Opart, const float* __restrict__ lpart,
    float* __restrict__ out)
{
    int cid = blockIdx.x * 256 + threadIdx.x;     // 262144 threads, 4 rows each
    int l  = cid & 63;
    int b  = (cid >> 6) & 3;
    int dt = (cid >> 8) & 3;
    int w  = (cid >> 10) & 3;
    int qb = cid >> 12;
    int la = l & 31, hi = l >> 5;
    int d  = dt * 32 + la;
    int rbase = qb * 128 + w * 32 + 8 * b + 4 * hi;   // + j
    size_t off = (size_t)qb * (128 * DDIM) + (size_t)w * 4096
               + (size_t)((dt * 4 + b) * 64 + l) * 4;
    const size_t S = (size_t)NTOK * DDIM;
    float num[4] = {0.f, 0.f, 0.f, 0.f};
    float den[4] = {0.f, 0.f, 0.f, 0.f};
#pragma unroll
    for (int s = 0; s < NSPLIT; s++) {
        uint2 v = *reinterpret_cast<const uint2*>(Opart + (size_t)s * S + off);
        const _Float16* h = reinterpret_cast<const _Float16*>(&v);
#pragma unroll
        for (int j = 0; j < 4; j++) num[j] += (float)h[j];
#pragma unroll
        for (int j = 0; j < 4; j++) den[j] += lpart[(size_t)s * NTOK + rbase + j];
    }
#pragma unroll
    for (int j = 0; j < 4; j++)
        out[(size_t)(rbase + j) * DDIM + d] = (den[j] > 0.f) ? num[j] / den[j] : 0.f;
}

// ---------------------------------------------------------------------------
extern "C" void kernel_launch(void* const* d_in, const int* in_sizes, int n_in,
                              void* d_out, int out_size, void* d_ws, size_t ws_size,
                              hipStream_t stream)
{
    const void* X = d_in[0]; const void* mask = d_in[1]; const void* W = d_in[2];
    {
        const void* x_ = nullptr; const void* m_ = nullptr; const void* w_ = nullptr;
        for (int i = 0; i < n_in; i++) {
            if (in_sizes[i] == 16777216) x_ = d_in[i];
            else if (in_sizes[i] == 67108864) m_ = d_in[i];
            else if (in_sizes[i] == 786432) w_ = d_in[i];
        }
        if (x_ && m_ && w_) { X = x_; mask = m_; W = w_; }
    }
    float* out = (float*)d_out;                 // fp32 [8192][128]

    char* ws = (char*)d_ws;
    unsigned short* Qb  = (unsigned short*)(ws);                    // 0..2 MB
    unsigned short* Kb  = (unsigned short*)(ws + (2ull << 20));     // 2..4
    unsigned short* VT  = (unsigned short*)(ws + (4ull << 20));     // 4..6
    unsigned long long* Mpk = (unsigned long long*)(ws + (6ull << 20)); // 6..14
    _Float16*       Opart = (_Float16*)(ws + (14ull << 20));        // 14..30
    unsigned short* Wbf = (unsigned short*)(ws + (14ull << 20));    // alias (dead before attn)
    unsigned short* Vb  = (unsigned short*)(ws + (14ull << 20) + (1536ull << 10)); // dead after vtrans
    float*          lpart = (float*)(ws + (30ull << 20));           // 30..30.25
    int*            flags = (int*)(ws + (30ull << 20) + (512ull << 10));
    unsigned short* Xbf = (unsigned short*)(ws + (32ull << 20));    // 32..64 MB (dead after qkv)

    detect_kernel<<<1, 64, 0, stream>>>((const unsigned int*)X, (const unsigned int*)mask, flags);
    conv_w<<<dim3(384), 256, 0, stream>>>(W, flags, Wbf);
    conv_x<<<dim3(8192), 256, 0, stream>>>(X, flags, Xbf);
    mask_pack<<<dim3(2048), 256, 0, stream>>>(mask, flags, (unsigned char*)Mpk);
    qkv_gemm<<<dim3(256, 3), 256, 0, stream>>>(Xbf, Wbf, Qb, Kb, Vb);
    vtrans<<<dim3(256, 4), 256, 0, stream>>>(Vb, VT);
    attn_part<<<dim3(NSPLIT, 64), 256, 0, stream>>>(Qb, Kb, VT, Mpk, Opart, lpart);
    combine<<<dim3(1024), 256, 0, stream>>>(Opart, lpart, out);
}

// Round 5
// 509.319 us; speedup vs baseline: 1.0676x; 1.0310x over previous
//
#include <hip/hip_runtime.h>
#include <hip/hip_bf16.h>

typedef __attribute__((ext_vector_type(8))) short short8;
typedef __attribute__((ext_vector_type(4))) float f32x4;
typedef __attribute__((ext_vector_type(16))) float f32x16;
typedef __attribute__((ext_vector_type(2))) unsigned int uint2v;

#define NTOK 8192
#define HCH  2048
#define DDIM 128
#define NSPLIT 8
#define KPS   (NTOK / NSPLIT)     // 1024
#define NITER (KPS / 64)          // 16

__device__ __forceinline__ unsigned short f2bf(float f) {
    __hip_bfloat16 h = __float2bfloat16(f);
    return *reinterpret_cast<unsigned short*>(&h);
}
__device__ __forceinline__ unsigned short f2h(float f) {
    _Float16 h = (_Float16)f;
    return *reinterpret_cast<unsigned short*>(&h);
}

// Direct global->LDS (width 16). LDS dest must be linear in lane order
// (wave-uniform base + lane*16); swizzle is applied on the SOURCE address.
__device__ __forceinline__ void gload_lds16(const void* g, void* l) {
    __builtin_amdgcn_global_load_lds(
        reinterpret_cast<const __attribute__((address_space(1))) unsigned int*>(
            reinterpret_cast<uintptr_t>(g)),
        reinterpret_cast<__attribute__((address_space(3))) unsigned int*>(
            reinterpret_cast<uintptr_t>(l)),
        16, 0, 0);
}

// ---------------------------------------------------------------------------
// Kernel 0: runtime dtype detection (one wave, parallel).
// ---------------------------------------------------------------------------
__global__ void detect_kernel(const unsigned int* __restrict__ X,
                              const unsigned int* __restrict__ M,
                              int* __restrict__ flags)
{
    const int lane = threadIdx.x & 63;
    unsigned int e = (X[lane] >> 7) & 0xFF;
    unsigned long long hb = __ballot(e >= 110 && e <= 140);

    bool w_ok = true, h_ok = true, b_ok = true;
#pragma unroll
    for (int i = 0; i < 16; i++) {
        unsigned int u = M[lane + 64 * i];
        if (!(u == 0u || u == 1u || u == 0x3F800000u)) w_ok = false;
        unsigned int h0 = u & 0xFFFFu, h1 = u >> 16;
        bool o0 = (h0 == 0u || h0 == 0x3F80u || h0 == 0x3C00u || h0 == 1u);
        bool o1 = (h1 == 0u || h1 == 0x3F80u || h1 == 0x3C00u || h1 == 1u);
        if (!(o0 && o1)) h_ok = false;
        unsigned int b0 = u & 0xFF, b1 = (u >> 8) & 0xFF,
                     b2 = (u >> 16) & 0xFF, b3 = u >> 24;
        if (b0 > 1u || b1 > 1u || b2 > 1u || b3 > 1u) b_ok = false;
    }
    bool allw = __all(w_ok), allh = __all(h_ok), allb = __all(b_ok);
    if (lane == 0) {
        flags[0] = (__popcll(hb) < 32) ? 1 : 0;
        flags[1] = allw ? 0 : (allb ? 1 : (allh ? 2 : 3));
    }
}

// ---------------------------------------------------------------------------
// Kernel 0b: W -> bf16.
// ---------------------------------------------------------------------------
__global__ __launch_bounds__(256) void conv_w(
    const void* __restrict__ Wv, const int* __restrict__ flags,
    unsigned short* __restrict__ Wbf)
{
    int t = blockIdx.x * 256 + threadIdx.x;
    size_t off = (size_t)t * 8;
    if (flags[0] != 0) {
        const float* Wf = (const float*)Wv;
        float4 a = *reinterpret_cast<const float4*>(Wf + off);
        float4 b = *reinterpret_cast<const float4*>(Wf + off + 4);
        unsigned short o[8] = { f2bf(a.x), f2bf(a.y), f2bf(a.z), f2bf(a.w),
                                f2bf(b.x), f2bf(b.y), f2bf(b.z), f2bf(b.w) };
        *reinterpret_cast<uint4*>(Wbf + off) = *reinterpret_cast<uint4*>(o);
    } else {
        *reinterpret_cast<uint4*>(Wbf + off) =
            *reinterpret_cast<const uint4*>((const unsigned short*)Wv + off);
    }
}

// ---------------------------------------------------------------------------
// Kernel 0x: X -> bf16 once.
// ---------------------------------------------------------------------------
__global__ __launch_bounds__(256) void conv_x(
    const void* __restrict__ Xv, const int* __restrict__ flags,
    unsigned short* __restrict__ Xbf)
{
    int t = blockIdx.x * 256 + threadIdx.x;
    size_t off = (size_t)t * 8;
    if (flags[0] != 0) {
        const float* Xf = (const float*)Xv;
        float4 a = *reinterpret_cast<const float4*>(Xf + off);
        float4 b = *reinterpret_cast<const float4*>(Xf + off + 4);
        unsigned short o[8] = { f2bf(a.x), f2bf(a.y), f2bf(a.z), f2bf(a.w),
                                f2bf(b.x), f2bf(b.y), f2bf(b.z), f2bf(b.w) };
        *reinterpret_cast<uint4*>(Xbf + off) = *reinterpret_cast<uint4*>(o);
    } else {
        *reinterpret_cast<uint4*>(Xbf + off) =
            *reinterpret_cast<const uint4*>((const unsigned short*)Xv + off);
    }
}

// ---------------------------------------------------------------------------
// Kernel 0c: mask -> 1 bit/elem (thread per output byte, coalesced).
// ---------------------------------------------------------------------------
__global__ __launch_bounds__(256) void mask_pack(
    const void* __restrict__ maskv, const int* __restrict__ flags,
    unsigned char* __restrict__ Mp)
{
    const int mmode = flags[1];
    const int NB = NTOK * (NTOK / 8);
    int t0 = blockIdx.x * 256 + threadIdx.x;
    for (int b = t0; b < NB; b += 2048 * 256) {
        unsigned int byte = 0;
        if (mmode == 0) {
            const uint4* p = reinterpret_cast<const uint4*>(
                (const unsigned int*)maskv + (size_t)b * 8);
            uint4 a = p[0], c = p[1];
            byte = (a.x != 0u) | ((a.y != 0u) << 1) | ((a.z != 0u) << 2) | ((a.w != 0u) << 3)
                 | ((c.x != 0u) << 4) | ((c.y != 0u) << 5) | ((c.z != 0u) << 6) | ((c.w != 0u) << 7);
        } else if (mmode == 1) {
            unsigned long long v = *reinterpret_cast<const unsigned long long*>(
                (const unsigned char*)maskv + (size_t)b * 8);
#pragma unroll
            for (int k = 0; k < 8; k++)
                byte |= (((v >> (8 * k)) & 0xFFull) != 0ull) << k;
        } else if (mmode == 2) {
            uint4 a = *reinterpret_cast<const uint4*>(
                (const unsigned short*)maskv + (size_t)b * 8);
            byte = ((a.x & 0xFFFFu) != 0u) | ((a.x >> 16 != 0u) << 1)
                 | (((a.y & 0xFFFFu) != 0u) << 2) | ((a.y >> 16 != 0u) << 3)
                 | (((a.z & 0xFFFFu) != 0u) << 4) | ((a.z >> 16 != 0u) << 5)
                 | (((a.w & 0xFFFFu) != 0u) << 6) | ((a.w >> 16 != 0u) << 7);
        } else {
            byte = ((const unsigned char*)maskv)[b];
        }
        Mp[b] = (unsigned char)byte;
    }
}

// ---------------------------------------------------------------------------
// Kernel 1: QKV projection (unchanged).
// ---------------------------------------------------------------------------
__global__ __launch_bounds__(256) void qkv_gemm(
    const unsigned short* __restrict__ Xbf, const unsigned short* __restrict__ Wbf,
    unsigned short* __restrict__ Qb, unsigned short* __restrict__ Kb,
    unsigned short* __restrict__ Vb)
{
    __shared__ unsigned short Wsm[128 * 64];
    __shared__ unsigned short Xsm[32 * 64];
    const int tid  = threadIdx.x;
    const int lane = tid & 63, w = tid >> 6;
    const int c = lane & 15, g = lane >> 4;
    const int q0 = blockIdx.x * 32;
    const int n0 = blockIdx.y * 128;

    f32x4 acc[4];
#pragma unroll
    for (int i = 0; i < 4; i++) acc[i] = (f32x4){0.f, 0.f, 0.f, 0.f};

    const int xrow = tid >> 3, xc8 = tid & 7;
    const int arow = (w & 1) * 16 + c;

    for (int kk = 0; kk < HCH; kk += 64) {
        __syncthreads();
#pragma unroll
        for (int i = 0; i < 4; i++) {
            int cid = tid + 256 * i;
            int n = cid >> 3, c8 = cid & 7;
            gload_lds16(Wbf + (size_t)(n0 + n) * HCH + kk + ((c8 ^ (n & 7)) * 8),
                        &Wsm[cid * 8]);
        }
        gload_lds16(Xbf + (size_t)(q0 + xrow) * HCH + kk + ((xc8 ^ (xrow & 7)) * 8),
                    &Xsm[tid * 8]);
        __syncthreads();
#pragma unroll
        for (int ks = 0; ks < 2; ks++) {
            short8 af = *reinterpret_cast<const short8*>(
                &Xsm[(arow * 8 + ((ks * 4 + g) ^ (c & 7))) * 8]);
#pragma unroll
            for (int nt = 0; nt < 4; nt++) {
                int n = (w >> 1) * 64 + nt * 16 + c;
                short8 bf = *reinterpret_cast<const short8*>(
                    &Wsm[(n * 8 + ((ks * 4 + g) ^ (c & 7))) * 8]);
                acc[nt] = __builtin_amdgcn_mfma_f32_16x16x32_bf16(af, bf, acc[nt], 0, 0, 0);
            }
        }
    }
    unsigned short* dst = (blockIdx.y == 0) ? Qb : (blockIdx.y == 1) ? Kb : Vb;
#pragma unroll
    for (int nt = 0; nt < 4; nt++) {
        int n = (w >> 1) * 64 + nt * 16 + c;
#pragma unroll
        for (int r = 0; r < 4; r++) {
            int rr = q0 + (w & 1) * 16 + g * 4 + r;
            dst[(size_t)rr * DDIM + n] = f2bf(acc[nt][r]);
        }
    }
}

// ---------------------------------------------------------------------------
// Kernel 2: V -> VT (unchanged).
// ---------------------------------------------------------------------------
__global__ __launch_bounds__(256) void vtrans(
    const unsigned short* __restrict__ V, unsigned short* __restrict__ VT)
{
    __shared__ unsigned short T[32 * 33];
    const int t = threadIdx.x;
    const int k0 = blockIdx.x * 32, d0 = blockIdx.y * 32;
    {
        int key = t >> 3, dq = (t & 7) * 4;
        ushort4 v = *reinterpret_cast<const ushort4*>(V + (size_t)(k0 + key) * DDIM + d0 + dq);
        T[(dq + 0) * 33 + key] = v.x;
        T[(dq + 1) * 33 + key] = v.y;
        T[(dq + 2) * 33 + key] = v.z;
        T[(dq + 3) * 33 + key] = v.w;
    }
    __syncthreads();
    {
        int d = t >> 3, kq = (t & 7) * 4;
        ushort4 o;
        o.x = T[d * 33 + kq + 0]; o.y = T[d * 33 + kq + 1];
        o.z = T[d * 33 + kq + 2]; o.w = T[d * 33 + kq + 3];
        *reinterpret_cast<ushort4*>(VT + (size_t)(d0 + d) * NTOK + k0 + kq) = o;
    }
}

// ---------------------------------------------------------------------------
// Kernel 3: flash partials v8 — 64 q-rows per wave (two 32-row chains A/B).
// Each LDS K-fragment feeds 2 QK MFMAs; each V-fragment feeds 2 PV MFMAs:
// LDS bytes per FLOP halved vs v7 (the binding resource). 256 blocks = 1/CU,
// 64 KB LDS, ~290 VGPR at 1 wave/SIMD (launch_bounds(256,1)).
// ---------------------------------------------------------------------------
__global__ __launch_bounds__(256, 1) void attn_part(
    const unsigned short* __restrict__ Qb, const unsigned short* __restrict__ Kb,
    const unsigned short* __restrict__ VT, const unsigned long long* __restrict__ Mp,
    _Float16* __restrict__ Opart, float* __restrict__ lpart)
{
    __shared__ unsigned short Ksm[2][64 * 128];   // 2 x 16 KB, [k][d] chunks swz
    __shared__ unsigned short Vsm[2][128 * 64];   // 2 x 16 KB, [d][k] chunks swz
    const int tid  = threadIdx.x;
    const int lane = tid & 63, w = tid >> 6;
    const int la = lane & 31, hi = lane >> 5;
    const int split = blockIdx.x;              // 0..7
    const int qb    = blockIdx.y;              // 0..31
    const int q0 = qb * 256;
    const int kbase = split * KPS;
    const int tb0 = kbase >> 6;
    const int qrowA = q0 + w * 64 + la;        // chain A q-row
    const int qrowB = qrowA + 32;              // chain B q-row

    auto stage = [&](int b, int tt) {
        const int k0s = kbase + tt * 64;
#pragma unroll
        for (int i = 0; i < 4; i++) {
            int cid = tid + 256 * i;
            int rowk = cid >> 4, c16 = cid & 15;
            gload_lds16(Kb + (size_t)(k0s + rowk) * DDIM + ((c16 ^ (rowk & 15)) * 8),
                        &Ksm[b][cid * 8]);
        }
#pragma unroll
        for (int i = 0; i < 4; i++) {
            int cid = tid + 256 * i;
            int d = cid >> 3, c8 = cid & 7;
            gload_lds16(VT + (size_t)d * NTOK + k0s + ((c8 ^ (d & 7)) * 8),
                        &Vsm[b][cid * 8]);
        }
    };

    // Q as B-fragment: lane la = q-col, k(d)=dstep*16 + hi*8 + j
    short8 qfA[8], qfB[8];
#pragma unroll
    for (int dstep = 0; dstep < 8; dstep++) {
        qfA[dstep] = *reinterpret_cast<const short8*>(
            Qb + (size_t)qrowA * DDIM + dstep * 16 + hi * 8);
        qfB[dstep] = *reinterpret_cast<const short8*>(
            Qb + (size_t)qrowB * DDIM + dstep * 16 + hi * 8);
    }

    f32x16 accO[2][4];
#pragma unroll
    for (int qh = 0; qh < 2; qh++)
#pragma unroll
        for (int dt = 0; dt < 4; dt++)
#pragma unroll
            for (int r = 0; r < 16; r++) accO[qh][dt][r] = 0.f;
    float LaccA = 0.f, LaccB = 0.f;

    unsigned long long mwA = Mp[(size_t)qrowA * 128 + tb0];
    unsigned long long mwB = Mp[(size_t)qrowB * 128 + tb0];
    unsigned long long mwnA = 0, mwnB = 0;

    stage(0, 0);                                  // prologue prefetch

    for (int t = 0; t < NITER; t++) {
        __syncthreads();                          // drains staged loads, 1/iter
        if (t + 1 < NITER) {
            stage((t + 1) & 1, t + 1);            // in flight across compute(t)
            mwnA = Mp[(size_t)qrowA * 128 + tb0 + t + 1];
            mwnB = Mp[(size_t)qrowB * 128 + tb0 + t + 1];
        }
        const unsigned short* Ks = Ksm[t & 1];
        const unsigned short* Vs = Vsm[t & 1];

        // ---- QK^T swapped: one K-fragment read feeds both Q-chains
        f32x16 S0A, S1A, S0B, S1B;
#pragma unroll
        for (int r = 0; r < 16; r++) { S0A[r] = 0.f; S1A[r] = 0.f; S0B[r] = 0.f; S1B[r] = 0.f; }
#pragma unroll
        for (int dstep = 0; dstep < 8; dstep++) {
            int slot = (2 * dstep + hi) ^ (la & 15);
            short8 k0f = *reinterpret_cast<const short8*>(&Ks[(la * 16 + slot) * 8]);
            short8 k1f = *reinterpret_cast<const short8*>(&Ks[((32 + la) * 16 + slot) * 8]);
            S0A = __builtin_amdgcn_mfma_f32_32x32x16_bf16(k0f, qfA[dstep], S0A, 0, 0, 0);
            S1A = __builtin_amdgcn_mfma_f32_32x32x16_bf16(k1f, qfA[dstep], S1A, 0, 0, 0);
            S0B = __builtin_amdgcn_mfma_f32_32x32x16_bf16(k0f, qfB[dstep], S0B, 0, 0, 0);
            S1B = __builtin_amdgcn_mfma_f32_32x32x16_bf16(k1f, qfB[dstep], S1B, 0, 0, 0);
        }

        // ---- mask + exp + pack to PV A-fragments (in-register, T12)
        short8 paA[4], paB[4];
        auto softpack = [&](const f32x16& S, int kt, short8* paP,
                            unsigned long long mh, float& Lacc) {
            float p[16];
#pragma unroll
            for (int r = 0; r < 16; r++) {
                int bit = kt * 32 + (r & 3) + 8 * (r >> 2);
                bool mv = (mh >> bit) & 1ull;
                float e = __expf(S[r] * 0.0078125f);   // exp(x/128)
                p[r] = mv ? 0.f : e;
                Lacc += p[r];
            }
            unsigned int U[4][2];
#pragma unroll
            for (int b = 0; b < 4; b++) {
                asm("v_cvt_pk_bf16_f32 %0, %1, %2"
                    : "=v"(U[b][0]) : "v"(p[4 * b + 0]), "v"(p[4 * b + 1]));
                asm("v_cvt_pk_bf16_f32 %0, %1, %2"
                    : "=v"(U[b][1]) : "v"(p[4 * b + 2]), "v"(p[4 * b + 3]));
            }
#pragma unroll
            for (int h = 0; h < 2; h++) {
                uint2v sA = __builtin_amdgcn_permlane32_swap(U[2 * h][0], U[2 * h + 1][0], false, false);
                uint2v sB = __builtin_amdgcn_permlane32_swap(U[2 * h][1], U[2 * h + 1][1], false, false);
                unsigned int fr[4] = { sA.x, sB.x, sA.y, sB.y };
                paP[h] = *reinterpret_cast<short8*>(fr);
            }
        };
        const unsigned long long mhA = mwA >> (4 * hi);
        const unsigned long long mhB = mwB >> (4 * hi);
        softpack(S0A, 0, &paA[0], mhA, LaccA);
        softpack(S1A, 1, &paA[2], mhA, LaccA);
        softpack(S0B, 0, &paB[0], mhB, LaccB);
        softpack(S1B, 1, &paB[2], mhB, LaccB);

        // ---- PV: one V-fragment read feeds both P-chains
#pragma unroll
        for (int s = 0; s < 4; s++) {
#pragma unroll
            for (int dt = 0; dt < 4; dt++) {
                int slot = (2 * s + hi) ^ (la & 7);
                short8 vf = *reinterpret_cast<const short8*>(
                    &Vs[((dt * 32 + la) * 8 + slot) * 8]);
                accO[0][dt] = __builtin_amdgcn_mfma_f32_32x32x16_bf16(paA[s], vf, accO[0][dt], 0, 0, 0);
                accO[1][dt] = __builtin_amdgcn_mfma_f32_32x32x16_bf16(paB[s], vf, accO[1][dt], 0, 0, 0);
            }
        }
        if (t + 1 < NITER) { mwA = mwnA; mwB = mwnB; }
    }

    // L: both hi-halves of a q-column hold complementary partial sums.
    LaccA += __shfl_xor(LaccA, 32, 64);
    LaccB += __shfl_xor(LaccB, 32, 64);

    // Fragment-contiguous Opart: wave chunk = 64 q x 128 d fp16 (16 KB).
    // lane holds q(within chain) = 8b + 4hi + j, d = dt*32 + la.
    _Float16* Ob = Opart + ((size_t)split * 32 + qb) * (256 * DDIM) + (size_t)w * 8192;
#pragma unroll
    for (int qh = 0; qh < 2; qh++)
#pragma unroll
        for (int dt = 0; dt < 4; dt++)
#pragma unroll
            for (int b = 0; b < 4; b++) {
                unsigned int w0 = (unsigned int)f2h(accO[qh][dt][4 * b + 0])
                                | ((unsigned int)f2h(accO[qh][dt][4 * b + 1]) << 16);
                unsigned int w1 = (unsigned int)f2h(accO[qh][dt][4 * b + 2])
                                | ((unsigned int)f2h(accO[qh][dt][4 * b + 3]) << 16);
                uint2 uv; uv.x = w0; uv.y = w1;
                *reinterpret_cast<uint2*>(
                    Ob + (size_t)((((qh * 4 + dt) * 4 + b) * 64 + lane) * 4)) = uv;
            }
    if (hi == 0) {
        lpart[(size_t)split * NTOK + q0 + w * 64 + la] = LaccA;
        lpart[(size_t)split * NTOK + q0 + w * 64 + 32 + la] = LaccB;
    }
}

// ---------------------------------------------------------------------------
// Kernel 4: combine v4 (inverts the v8 fragment layout; 8-B reads/split).
// ---------------------------------------------------------------------------
__global__ __launch_bounds__(256) void combine(
    const _Float16* __restrict__ Opart, const float* __restrict__ lpart,
    float* __restrict__ out)
{
    int cid = blockIdx.x * 256 + threadIdx.x;     // 262144 threads, 4 rows each
    int l  = cid & 63;
    int b  = (cid >> 6) & 3;
    int dt = (cid >> 8) & 3;
    int qh = (cid >> 10) & 1;
    int w  = (cid >> 11) & 3;
    int qb = cid >> 13;                           // 0..31
    int la = l & 31, hi = l >> 5;
    int d  = dt * 32 + la;
    int rbase = qb * 256 + w * 64 + qh * 32 + 8 * b + 4 * hi;   // + j
    size_t off = (size_t)qb * (256 * DDIM) + (size_t)w * 8192
               + (size_t)((((qh * 4 + dt) * 4 + b) * 64 + l) * 4);
    const size_t S = (size_t)NTOK * DDIM;
    float num[4] = {0.f, 0.f, 0.f, 0.f};
    float den[4] = {0.f, 0.f, 0.f, 0.f};
#pragma unroll
    for (int s = 0; s < NSPLIT; s++) {
        uint2 v = *reinterpret_cast<const uint2*>(Opart + (size_t)s * S + off);
        const _Float16* h = reinterpret_cast<const _Float16*>(&v);
#pragma unroll
        for (int j = 0; j < 4; j++) num[j] += (float)h[j];
#pragma unroll
        for (int j = 0; j < 4; j++) den[j] += lpart[(size_t)s * NTOK + rbase + j];
    }
#pragma unroll
    for (int j = 0; j < 4; j++)
        out[(size_t)(rbase + j) * DDIM + d] = (den[j] > 0.f) ? num[j] / den[j] : 0.f;
}

// ---------------------------------------------------------------------------
extern "C" void kernel_launch(void* const* d_in, const int* in_sizes, int n_in,
                              void* d_out, int out_size, void* d_ws, size_t ws_size,
                              hipStream_t stream)
{
    const void* X = d_in[0]; const void* mask = d_in[1]; const void* W = d_in[2];
    {
        const void* x_ = nullptr; const void* m_ = nullptr; const void* w_ = nullptr;
        for (int i = 0; i < n_in; i++) {
            if (in_sizes[i] == 16777216) x_ = d_in[i];
            else if (in_sizes[i] == 67108864) m_ = d_in[i];
            else if (in_sizes[i] == 786432) w_ = d_in[i];
        }
        if (x_ && m_ && w_) { X = x_; mask = m_; W = w_; }
    }
    float* out = (float*)d_out;                 // fp32 [8192][128]

    char* ws = (char*)d_ws;
    unsigned short* Qb  = (unsigned short*)(ws);                    // 0..2 MB
    unsigned short* Kb  = (unsigned short*)(ws + (2ull << 20));     // 2..4
    unsigned short* VT  = (unsigned short*)(ws + (4ull << 20));     // 4..6
    unsigned long long* Mpk = (unsigned long long*)(ws + (6ull << 20)); // 6..14
    _Float16*       Opart = (_Float16*)(ws + (14ull << 20));        // 14..30
    unsigned short* Wbf = (unsigned short*)(ws + (14ull << 20));    // alias (dead before attn)
    unsigned short* Vb  = (unsigned short*)(ws + (14ull << 20) + (1536ull << 10)); // dead after vtrans
    float*          lpart = (float*)(ws + (30ull << 20));           // 30..30.25
    int*            flags = (int*)(ws + (30ull << 20) + (512ull << 10));
    unsigned short* Xbf = (unsigned short*)(ws + (32ull << 20));    // 32..64 MB (dead after qkv)

    detect_kernel<<<1, 64, 0, stream>>>((const unsigned int*)X, (const unsigned int*)mask, flags);
    conv_w<<<dim3(384), 256, 0, stream>>>(W, flags, Wbf);
    conv_x<<<dim3(8192), 256, 0, stream>>>(X, flags, Xbf);
    mask_pack<<<dim3(2048), 256, 0, stream>>>(mask, flags, (unsigned char*)Mpk);
    qkv_gemm<<<dim3(256, 3), 256, 0, stream>>>(Xbf, Wbf, Qb, Kb, Vb);
    vtrans<<<dim3(256, 4), 256, 0, stream>>>(Vb, VT);
    attn_part<<<dim3(NSPLIT, 32), 256, 0, stream>>>(Qb, Kb, VT, Mpk, Opart, lpart);
    combine<<<dim3(1024), 256, 0, stream>>>(Opart, lpart, out);
}

// Round 7
// 499.239 us; speedup vs baseline: 1.0892x; 1.0202x over previous
//
#include <hip/hip_runtime.h>
#include <hip/hip_bf16.h>

typedef __attribute__((ext_vector_type(8))) short short8;
typedef __attribute__((ext_vector_type(4))) float f32x4;
typedef __attribute__((ext_vector_type(16))) float f32x16;
typedef __attribute__((ext_vector_type(2))) unsigned int uint2v;

#define NTOK 8192
#define HCH  2048
#define DDIM 128
#define NSPLIT 8
#define KPS   (NTOK / NSPLIT)     // 1024
#define NITER (KPS / 64)          // 16

__device__ __forceinline__ unsigned short f2bf(float f) {
    __hip_bfloat16 h = __float2bfloat16(f);
    return *reinterpret_cast<unsigned short*>(&h);
}
__device__ __forceinline__ unsigned short f2h(float f) {
    _Float16 h = (_Float16)f;
    return *reinterpret_cast<unsigned short*>(&h);
}

// Direct global->LDS (width 16). LDS dest must be linear in lane order
// (wave-uniform base + lane*16); swizzle is applied on the SOURCE address.
__device__ __forceinline__ void gload_lds16(const void* g, void* l) {
    __builtin_amdgcn_global_load_lds(
        reinterpret_cast<const __attribute__((address_space(1))) unsigned int*>(
            reinterpret_cast<uintptr_t>(g)),
        reinterpret_cast<__attribute__((address_space(3))) unsigned int*>(
            reinterpret_cast<uintptr_t>(l)),
        16, 0, 0);
}

// ---------------------------------------------------------------------------
// Kernel 0: runtime dtype detection (one wave, parallel).
// ---------------------------------------------------------------------------
__global__ void detect_kernel(const unsigned int* __restrict__ X,
                              const unsigned int* __restrict__ M,
                              int* __restrict__ flags)
{
    const int lane = threadIdx.x & 63;
    unsigned int e = (X[lane] >> 7) & 0xFF;
    unsigned long long hb = __ballot(e >= 110 && e <= 140);

    bool w_ok = true, h_ok = true, b_ok = true;
#pragma unroll
    for (int i = 0; i < 16; i++) {
        unsigned int u = M[lane + 64 * i];
        if (!(u == 0u || u == 1u || u == 0x3F800000u)) w_ok = false;
        unsigned int h0 = u & 0xFFFFu, h1 = u >> 16;
        bool o0 = (h0 == 0u || h0 == 0x3F80u || h0 == 0x3C00u || h0 == 1u);
        bool o1 = (h1 == 0u || h1 == 0x3F80u || h1 == 0x3C00u || h1 == 1u);
        if (!(o0 && o1)) h_ok = false;
        unsigned int b0 = u & 0xFF, b1 = (u >> 8) & 0xFF,
                     b2 = (u >> 16) & 0xFF, b3 = u >> 24;
        if (b0 > 1u || b1 > 1u || b2 > 1u || b3 > 1u) b_ok = false;
    }
    bool allw = __all(w_ok), allh = __all(h_ok), allb = __all(b_ok);
    if (lane == 0) {
        flags[0] = (__popcll(hb) < 32) ? 1 : 0;
        flags[1] = allw ? 0 : (allb ? 1 : (allh ? 2 : 3));
    }
}

// ---------------------------------------------------------------------------
// Kernel 0bx: fused X -> bf16 (blocks 0..8191) and W -> bf16 (blocks 8192+).
// ---------------------------------------------------------------------------
__global__ __launch_bounds__(256) void conv_xw(
    const void* __restrict__ Xv, const void* __restrict__ Wv,
    const int* __restrict__ flags,
    unsigned short* __restrict__ Xbf, unsigned short* __restrict__ Wbf)
{
    const bool isW = (blockIdx.x >= 8192);
    const void* src = isW ? Wv : Xv;
    unsigned short* dst = isW ? Wbf : Xbf;
    int t = (isW ? (blockIdx.x - 8192) : blockIdx.x) * 256 + threadIdx.x;
    size_t off = (size_t)t * 8;
    if (flags[0] != 0) {
        const float* Sf = (const float*)src;
        float4 a = *reinterpret_cast<const float4*>(Sf + off);
        float4 b = *reinterpret_cast<const float4*>(Sf + off + 4);
        unsigned short o[8] = { f2bf(a.x), f2bf(a.y), f2bf(a.z), f2bf(a.w),
                                f2bf(b.x), f2bf(b.y), f2bf(b.z), f2bf(b.w) };
        *reinterpret_cast<uint4*>(dst + off) = *reinterpret_cast<uint4*>(o);
    } else {
        *reinterpret_cast<uint4*>(dst + off) =
            *reinterpret_cast<const uint4*>((const unsigned short*)src + off);
    }
}

// ---------------------------------------------------------------------------
// Kernel 0c: mask -> 1 bit/elem (thread per output byte, coalesced).
// ---------------------------------------------------------------------------
__global__ __launch_bounds__(256) void mask_pack(
    const void* __restrict__ maskv, const int* __restrict__ flags,
    unsigned char* __restrict__ Mp)
{
    const int mmode = flags[1];
    const int NB = NTOK * (NTOK / 8);
    int t0 = blockIdx.x * 256 + threadIdx.x;
    for (int b = t0; b < NB; b += 2048 * 256) {
        unsigned int byte = 0;
        if (mmode == 0) {
            const uint4* p = reinterpret_cast<const uint4*>(
                (const unsigned int*)maskv + (size_t)b * 8);
            uint4 a = p[0], c = p[1];
            byte = (a.x != 0u) | ((a.y != 0u) << 1) | ((a.z != 0u) << 2) | ((a.w != 0u) << 3)
                 | ((c.x != 0u) << 4) | ((c.y != 0u) << 5) | ((c.z != 0u) << 6) | ((c.w != 0u) << 7);
        } else if (mmode == 1) {
            unsigned long long v = *reinterpret_cast<const unsigned long long*>(
                (const unsigned char*)maskv + (size_t)b * 8);
#pragma unroll
            for (int k = 0; k < 8; k++)
                byte |= (((v >> (8 * k)) & 0xFFull) != 0ull) << k;
        } else if (mmode == 2) {
            uint4 a = *reinterpret_cast<const uint4*>(
                (const unsigned short*)maskv + (size_t)b * 8);
            byte = ((a.x & 0xFFFFu) != 0u) | ((a.x >> 16 != 0u) << 1)
                 | (((a.y & 0xFFFFu) != 0u) << 2) | ((a.y >> 16 != 0u) << 3)
                 | (((a.z & 0xFFFFu) != 0u) << 4) | ((a.z >> 16 != 0u) << 5)
                 | (((a.w & 0xFFFFu) != 0u) << 6) | ((a.w >> 16 != 0u) << 7);
        } else {
            byte = ((const unsigned char*)maskv)[b];
        }
        Mp[b] = (unsigned char)byte;
    }
}

// ---------------------------------------------------------------------------
// Kernel 1: QKV projection v3 — 128x128 tile (m97 geometry), double-buffered
// global_load_lds staging (one barrier/iter), 4 waves x (64x64 via 4x4
// 16x16x32 frags). MFMA:LDS-read ratio 2:1 (was 8:10).
// ---------------------------------------------------------------------------
__global__ __launch_bounds__(256) void qkv_gemm(
    const unsigned short* __restrict__ Xbf, const unsigned short* __restrict__ Wbf,
    unsigned short* __restrict__ Qb, unsigned short* __restrict__ Kb,
    unsigned short* __restrict__ Vb)
{
    __shared__ unsigned short Xsm[2][128 * 64];   // 2 x 16 KB
    __shared__ unsigned short Wsm[2][128 * 64];   // 2 x 16 KB
    const int tid  = threadIdx.x;
    const int lane = tid & 63, w = tid >> 6;
    const int c = lane & 15, g = lane >> 4;
    const int q0 = blockIdx.x * 128;
    const int n0 = blockIdx.y * 128;

    auto stage = [&](int b, int kk) {
#pragma unroll
        for (int i = 0; i < 4; i++) {
            int cid = tid + 256 * i;
            int row = cid >> 3, c8 = cid & 7;
            gload_lds16(Xbf + (size_t)(q0 + row) * HCH + kk + ((c8 ^ (row & 7)) * 8),
                        &Xsm[b][cid * 8]);
        }
#pragma unroll
        for (int i = 0; i < 4; i++) {
            int cid = tid + 256 * i;
            int row = cid >> 3, c8 = cid & 7;
            gload_lds16(Wbf + (size_t)(n0 + row) * HCH + kk + ((c8 ^ (row & 7)) * 8),
                        &Wsm[b][cid * 8]);
        }
    };

    f32x4 acc[4][4];
#pragma unroll
    for (int mt = 0; mt < 4; mt++)
#pragma unroll
        for (int nt = 0; nt < 4; nt++) acc[mt][nt] = (f32x4){0.f, 0.f, 0.f, 0.f};

    stage(0, 0);                                  // prologue prefetch

    const int NKIT = HCH / 64;                    // 32
    for (int t = 0; t < NKIT; t++) {
        __syncthreads();                          // drains staged loads, 1/iter
        if (t + 1 < NKIT) stage((t + 1) & 1, (t + 1) * 64);
        const unsigned short* Xs = Xsm[t & 1];
        const unsigned short* Ws = Wsm[t & 1];
#pragma unroll
        for (int ks = 0; ks < 2; ks++) {
            const int slot = (ks * 4 + g) ^ (c & 7);
            short8 af[4], bf[4];
#pragma unroll
            for (int mt = 0; mt < 4; mt++) {
                int a = (w & 1) * 64 + mt * 16 + c;          // a&7 == c&7
                af[mt] = *reinterpret_cast<const short8*>(&Xs[(a * 8 + slot) * 8]);
            }
#pragma unroll
            for (int nt = 0; nt < 4; nt++) {
                int b = (w >> 1) * 64 + nt * 16 + c;         // b&7 == c&7
                bf[nt] = *reinterpret_cast<const short8*>(&Ws[(b * 8 + slot) * 8]);
            }
#pragma unroll
            for (int mt = 0; mt < 4; mt++)
#pragma unroll
                for (int nt = 0; nt < 4; nt++)
                    acc[mt][nt] = __builtin_amdgcn_mfma_f32_16x16x32_bf16(
                        af[mt], bf[nt], acc[mt][nt], 0, 0, 0);
        }
    }
    unsigned short* dst = (blockIdx.y == 0) ? Qb : (blockIdx.y == 1) ? Kb : Vb;
#pragma unroll
    for (int mt = 0; mt < 4; mt++)
#pragma unroll
        for (int nt = 0; nt < 4; nt++) {
            int col = (w >> 1) * 64 + nt * 16 + c;
#pragma unroll
            for (int r = 0; r < 4; r++) {
                int rr = q0 + (w & 1) * 64 + mt * 16 + g * 4 + r;
                dst[(size_t)rr * DDIM + col] = f2bf(acc[mt][nt][r]);
            }
        }
}

// ---------------------------------------------------------------------------
// Kernel 2: V -> VT (unchanged).
// ---------------------------------------------------------------------------
__global__ __launch_bounds__(256) void vtrans(
    const unsigned short* __restrict__ V, unsigned short* __restrict__ VT)
{
    __shared__ unsigned short T[32 * 33];
    const int t = threadIdx.x;
    const int k0 = blockIdx.x * 32, d0 = blockIdx.y * 32;
    {
        int key = t >> 3, dq = (t & 7) * 4;
        ushort4 v = *reinterpret_cast<const ushort4*>(V + (size_t)(k0 + key) * DDIM + d0 + dq);
        T[(dq + 0) * 33 + key] = v.x;
        T[(dq + 1) * 33 + key] = v.y;
        T[(dq + 2) * 33 + key] = v.z;
        T[(dq + 3) * 33 + key] = v.w;
    }
    __syncthreads();
    {
        int d = t >> 3, kq = (t & 7) * 4;
        ushort4 o;
        o.x = T[d * 33 + kq + 0]; o.y = T[d * 33 + kq + 1];
        o.z = T[d * 33 + kq + 2]; o.w = T[d * 33 + kq + 3];
        *reinterpret_cast<ushort4*>(VT + (size_t)(d0 + d) * NTOK + k0 + kq) = o;
    }
}

// ---------------------------------------------------------------------------
// Kernel 3: flash partials v8 (unchanged from round 5).
// ---------------------------------------------------------------------------
__global__ __launch_bounds__(256, 1) void attn_part(
    const unsigned short* __restrict__ Qb, const unsigned short* __restrict__ Kb,
    const unsigned short* __restrict__ VT, const unsigned long long* __restrict__ Mp,
    _Float16* __restrict__ Opart, float* __restrict__ lpart)
{
    __shared__ unsigned short Ksm[2][64 * 128];   // 2 x 16 KB, [k][d] chunks swz
    __shared__ unsigned short Vsm[2][128 * 64];   // 2 x 16 KB, [d][k] chunks swz
    const int tid  = threadIdx.x;
    const int lane = tid & 63, w = tid >> 6;
    const int la = lane & 31, hi = lane >> 5;
    const int split = blockIdx.x;              // 0..7
    const int qb    = blockIdx.y;              // 0..31
    const int q0 = qb * 256;
    const int kbase = split * KPS;
    const int tb0 = kbase >> 6;
    const int qrowA = q0 + w * 64 + la;        // chain A q-row
    const int qrowB = qrowA + 32;              // chain B q-row

    auto stage = [&](int b, int tt) {
        const int k0s = kbase + tt * 64;
#pragma unroll
        for (int i = 0; i < 4; i++) {
            int cid = tid + 256 * i;
            int rowk = cid >> 4, c16 = cid & 15;
            gload_lds16(Kb + (size_t)(k0s + rowk) * DDIM + ((c16 ^ (rowk & 15)) * 8),
                        &Ksm[b][cid * 8]);
        }
#pragma unroll
        for (int i = 0; i < 4; i++) {
            int cid = tid + 256 * i;
            int d = cid >> 3, c8 = cid & 7;
            gload_lds16(VT + (size_t)d * NTOK + k0s + ((c8 ^ (d & 7)) * 8),
                        &Vsm[b][cid * 8]);
        }
    };

    // Q as B-fragment: lane la = q-col, k(d)=dstep*16 + hi*8 + j
    short8 qfA[8], qfB[8];
#pragma unroll
    for (int dstep = 0; dstep < 8; dstep++) {
        qfA[dstep] = *reinterpret_cast<const short8*>(
            Qb + (size_t)qrowA * DDIM + dstep * 16 + hi * 8);
        qfB[dstep] = *reinterpret_cast<const short8*>(
            Qb + (size_t)qrowB * DDIM + dstep * 16 + hi * 8);
    }

    f32x16 accO[2][4];
#pragma unroll
    for (int qh = 0; qh < 2; qh++)
#pragma unroll
        for (int dt = 0; dt < 4; dt++)
#pragma unroll
            for (int r = 0; r < 16; r++) accO[qh][dt][r] = 0.f;
    float LaccA = 0.f, LaccB = 0.f;

    unsigned long long mwA = Mp[(size_t)qrowA * 128 + tb0];
    unsigned long long mwB = Mp[(size_t)qrowB * 128 + tb0];
    unsigned long long mwnA = 0, mwnB = 0;

    stage(0, 0);                                  // prologue prefetch

    for (int t = 0; t < NITER; t++) {
        __syncthreads();                          // drains staged loads, 1/iter
        if (t + 1 < NITER) {
            stage((t + 1) & 1, t + 1);            // in flight across compute(t)
            mwnA = Mp[(size_t)qrowA * 128 + tb0 + t + 1];
            mwnB = Mp[(size_t)qrowB * 128 + tb0 + t + 1];
        }
        const unsigned short* Ks = Ksm[t & 1];
        const unsigned short* Vs = Vsm[t & 1];

        // ---- QK^T swapped: one K-fragment read feeds both Q-chains
        f32x16 S0A, S1A, S0B, S1B;
#pragma unroll
        for (int r = 0; r < 16; r++) { S0A[r] = 0.f; S1A[r] = 0.f; S0B[r] = 0.f; S1B[r] = 0.f; }
#pragma unroll
        for (int dstep = 0; dstep < 8; dstep++) {
            int slot = (2 * dstep + hi) ^ (la & 15);
            short8 k0f = *reinterpret_cast<const short8*>(&Ks[(la * 16 + slot) * 8]);
            short8 k1f = *reinterpret_cast<const short8*>(&Ks[((32 + la) * 16 + slot) * 8]);
            S0A = __builtin_amdgcn_mfma_f32_32x32x16_bf16(k0f, qfA[dstep], S0A, 0, 0, 0);
            S1A = __builtin_amdgcn_mfma_f32_32x32x16_bf16(k1f, qfA[dstep], S1A, 0, 0, 0);
            S0B = __builtin_amdgcn_mfma_f32_32x32x16_bf16(k0f, qfB[dstep], S0B, 0, 0, 0);
            S1B = __builtin_amdgcn_mfma_f32_32x32x16_bf16(k1f, qfB[dstep], S1B, 0, 0, 0);
        }

        // ---- mask + exp + pack to PV A-fragments (in-register, T12)
        short8 paA[4], paB[4];
        auto softpack = [&](const f32x16& S, int kt, short8* paP,
                            unsigned long long mh, float& Lacc) {
            float p[16];
#pragma unroll
            for (int r = 0; r < 16; r++) {
                int bit = kt * 32 + (r & 3) + 8 * (r >> 2);
                bool mv = (mh >> bit) & 1ull;
                float e = __expf(S[r] * 0.0078125f);   // exp(x/128)
                p[r] = mv ? 0.f : e;
                Lacc += p[r];
            }
            unsigned int U[4][2];
#pragma unroll
            for (int b = 0; b < 4; b++) {
                asm("v_cvt_pk_bf16_f32 %0, %1, %2"
                    : "=v"(U[b][0]) : "v"(p[4 * b + 0]), "v"(p[4 * b + 1]));
                asm("v_cvt_pk_bf16_f32 %0, %1, %2"
                    : "=v"(U[b][1]) : "v"(p[4 * b + 2]), "v"(p[4 * b + 3]));
            }
#pragma unroll
            for (int h = 0; h < 2; h++) {
                uint2v sA = __builtin_amdgcn_permlane32_swap(U[2 * h][0], U[2 * h + 1][0], false, false);
                uint2v sB = __builtin_amdgcn_permlane32_swap(U[2 * h][1], U[2 * h + 1][1], false, false);
                unsigned int fr[4] = { sA.x, sB.x, sA.y, sB.y };
                paP[h] = *reinterpret_cast<short8*>(fr);
            }
        };
        const unsigned long long mhA = mwA >> (4 * hi);
        const unsigned long long mhB = mwB >> (4 * hi);
        softpack(S0A, 0, &paA[0], mhA, LaccA);
        softpack(S1A, 1, &paA[2], mhA, LaccA);
        softpack(S0B, 0, &paB[0], mhB, LaccB);
        softpack(S1B, 1, &paB[2], mhB, LaccB);

        // ---- PV: one V-fragment read feeds both P-chains
#pragma unroll
        for (int s = 0; s < 4; s++) {
#pragma unroll
            for (int dt = 0; dt < 4; dt++) {
                int slot = (2 * s + hi) ^ (la & 7);
                short8 vf = *reinterpret_cast<const short8*>(
                    &Vs[((dt * 32 + la) * 8 + slot) * 8]);
                accO[0][dt] = __builtin_amdgcn_mfma_f32_32x32x16_bf16(paA[s], vf, accO[0][dt], 0, 0, 0);
                accO[1][dt] = __builtin_amdgcn_mfma_f32_32x32x16_bf16(paB[s], vf, accO[1][dt], 0, 0, 0);
            }
        }
        if (t + 1 < NITER) { mwA = mwnA; mwB = mwnB; }
    }

    // L: both hi-halves of a q-column hold complementary partial sums.
    LaccA += __shfl_xor(LaccA, 32, 64);
    LaccB += __shfl_xor(LaccB, 32, 64);

    // Fragment-contiguous Opart: wave chunk = 64 q x 128 d fp16 (16 KB).
    // lane holds q(within chain) = 8b + 4hi + j, d = dt*32 + la.
    _Float16* Ob = Opart + ((size_t)split * 32 + qb) * (256 * DDIM) + (size_t)w * 8192;
#pragma unroll
    for (int qh = 0; qh < 2; qh++)
#pragma unroll
        for (int dt = 0; dt < 4; dt++)
#pragma unroll
            for (int b = 0; b < 4; b++) {
                unsigned int w0 = (unsigned int)f2h(accO[qh][dt][4 * b + 0])
                                | ((unsigned int)f2h(accO[qh][dt][4 * b + 1]) << 16);
                unsigned int w1 = (unsigned int)f2h(accO[qh][dt][4 * b + 2])
                                | ((unsigned int)f2h(accO[qh][dt][4 * b + 3]) << 16);
                uint2 uv; uv.x = w0; uv.y = w1;
                *reinterpret_cast<uint2*>(
                    Ob + (size_t)((((qh * 4 + dt) * 4 + b) * 64 + lane) * 4)) = uv;
            }
    if (hi == 0) {
        lpart[(size_t)split * NTOK + q0 + w * 64 + la] = LaccA;
        lpart[(size_t)split * NTOK + q0 + w * 64 + 32 + la] = LaccB;
    }
}

// ---------------------------------------------------------------------------
// Kernel 4: combine v4 (unchanged from round 5).
// ---------------------------------------------------------------------------
__global__ __launch_bounds__(256) void combine(
    const _Float16* __restrict__ Opart, const float* __restrict__ lpart,
    float* __restrict__ out)
{
    int cid = blockIdx.x * 256 + threadIdx.x;     // 262144 threads, 4 rows each
    int l  = cid & 63;
    int b  = (cid >> 6) & 3;
    int dt = (cid >> 8) & 3;
    int qh = (cid >> 10) & 1;
    int w  = (cid >> 11) & 3;
    int qb = cid >> 13;                           // 0..31
    int la = l & 31, hi = l >> 5;
    int d  = dt * 32 + la;
    int rbase = qb * 256 + w * 64 + qh * 32 + 8 * b + 4 * hi;   // + j
    size_t off = (size_t)qb * (256 * DDIM) + (size_t)w * 8192
               + (size_t)((((qh * 4 + dt) * 4 + b) * 64 + l) * 4);
    const size_t S = (size_t)NTOK * DDIM;
    float num[4] = {0.f, 0.f, 0.f, 0.f};
    float den[4] = {0.f, 0.f, 0.f, 0.f};
#pragma unroll
    for (int s = 0; s < NSPLIT; s++) {
        uint2 v = *reinterpret_cast<const uint2*>(Opart + (size_t)s * S + off);
        const _Float16* h = reinterpret_cast<const _Float16*>(&v);
#pragma unroll
        for (int j = 0; j < 4; j++) num[j] += (float)h[j];
#pragma unroll
        for (int j = 0; j < 4; j++) den[j] += lpart[(size_t)s * NTOK + rbase + j];
    }
#pragma unroll
    for (int j = 0; j < 4; j++)
        out[(size_t)(rbase + j) * DDIM + d] = (den[j] > 0.f) ? num[j] / den[j] : 0.f;
}

// ---------------------------------------------------------------------------
extern "C" void kernel_launch(void* const* d_in, const int* in_sizes, int n_in,
                              void* d_out, int out_size, void* d_ws, size_t ws_size,
                              hipStream_t stream)
{
    const void* X = d_in[0]; const void* mask = d_in[1]; const void* W = d_in[2];
    {
        const void* x_ = nullptr; const void* m_ = nullptr; const void* w_ = nullptr;
        for (int i = 0; i < n_in; i++) {
            if (in_sizes[i] == 16777216) x_ = d_in[i];
            else if (in_sizes[i] == 67108864) m_ = d_in[i];
            else if (in_sizes[i] == 786432) w_ = d_in[i];
        }
        if (x_ && m_ && w_) { X = x_; mask = m_; W = w_; }
    }
    float* out = (float*)d_out;                 // fp32 [8192][128]

    char* ws = (char*)d_ws;
    unsigned short* Qb  = (unsigned short*)(ws);                    // 0..2 MB
    unsigned short* Kb  = (unsigned short*)(ws + (2ull << 20));     // 2..4
    unsigned short* VT  = (unsigned short*)(ws + (4ull << 20));     // 4..6
    unsigned long long* Mpk = (unsigned long long*)(ws + (6ull << 20)); // 6..14
    _Float16*       Opart = (_Float16*)(ws + (14ull << 20));        // 14..30
    unsigned short* Wbf = (unsigned short*)(ws + (14ull << 20));    // alias (dead before attn)
    unsigned short* Vb  = (unsigned short*)(ws + (14ull << 20) + (1536ull << 10)); // dead after vtrans
    float*          lpart = (float*)(ws + (30ull << 20));           // 30..30.25
    int*            flags = (int*)(ws + (30ull << 20) + (512ull << 10));
    unsigned short* Xbf = (unsigned short*)(ws + (32ull << 20));    // 32..64 MB (dead after qkv)

    detect_kernel<<<1, 64, 0, stream>>>((const unsigned int*)X, (const unsigned int*)mask, flags);
    conv_xw<<<dim3(8192 + 384), 256, 0, stream>>>(X, W, flags, Xbf, Wbf);
    mask_pack<<<dim3(2048), 256, 0, stream>>>(mask, flags, (unsigned char*)Mpk);
    qkv_gemm<<<dim3(64, 3), 256, 0, stream>>>(Xbf, Wbf, Qb, Kb, Vb);
    vtrans<<<dim3(256, 4), 256, 0, stream>>>(Vb, VT);
    attn_part<<<dim3(NSPLIT, 32), 256, 0, stream>>>(Qb, Kb, VT, Mpk, Opart, lpart);
    combine<<<dim3(1024), 256, 0, stream>>>(Opart, lpart, out);
}